// Round 5
// baseline (478.946 us; speedup 1.0000x reference)
//
#include <hip/hip_runtime.h>

// DiffAttn on MI355X, round 12.
// Rounds 10/11 post-mortem: hand-phased lockstep (barrier/lgkm(0)/MFMA/barrier
// x2-4 per K-tile) convoys all 8 waves -> LDS and MFMA pipes strictly
// serialize; 4-phase == 2-phase == 140us proved phase machinery isn't the
// lever. This round REMOVES the phases: B is triple-buffered (LDS 160 KB =
// A dbuf 2x32K + B tbuf 3x32K) so B(t+2) never lands in the live B buffer,
// which cuts the K-tile to ONE barrier with a counted vmcnt(4) and lets the
// compiler software-pipeline ds_read<->MFMA (m97: compiler lgkm scheduling is
// near-optimal) while waves desync within the tile (m114 overlap).
// Ledger per thread per tile t: issue [A(t+1)x4, B(t+2)x4] at tile start
// (full-tile landing window); at tile end outstanding oldest-first =
// [B(t+1)x4, A(t+1)x4, B(t+2)x4]; vmcnt(4) lands A(t+1)+B(t+1), keeps
// B(t+2) in flight. apply_pv / epilogues / layouts unchanged (verified).

typedef unsigned short u16;
typedef short    bf16x8 __attribute__((ext_vector_type(8)));
typedef unsigned short u16x8 __attribute__((ext_vector_type(8)));
typedef unsigned short u16x4 __attribute__((ext_vector_type(4)));
typedef float    f32x4  __attribute__((ext_vector_type(4)));

typedef __attribute__((address_space(3))) unsigned int       lds_uint;
typedef __attribute__((address_space(1))) const unsigned int gl_uint;

__device__ __forceinline__ void glds16(const void* g, void* l) {
  __builtin_amdgcn_global_load_lds((gl_uint*)g, (lds_uint*)l, 16, 0, 0);
}

__device__ __forceinline__ u16 to_bf16(float f) {
  unsigned u = __float_as_uint(f);
  return (u16)((u + 0x7FFFu + ((u >> 16) & 1u)) >> 16);  // RNE
}
__device__ __forceinline__ float b2f(u16 h) {
  return __uint_as_float(((unsigned)h) << 16);
}

// ---------------- conversion kernels ----------------

__global__ void cvt_x(const float4* __restrict__ in, u16x4* __restrict__ out, int n4) {
  int i = blockIdx.x * 256 + threadIdx.x;
  if (i >= n4) return;
  float4 v = in[i];
  u16x4 o;
  o[0] = to_bf16(v.x); o[1] = to_bf16(v.y); o[2] = to_bf16(v.z); o[3] = to_bf16(v.w);
  out[i] = o;
}

__global__ void transpose_cvt(const float* __restrict__ in, u16* __restrict__ out,
                              int R, int C) {
  __shared__ float t[64][65];
  int c0 = blockIdx.x * 64, r0 = blockIdx.y * 64;
  int tx = threadIdx.x, ty = threadIdx.y;
  #pragma unroll
  for (int i = 0; i < 64; i += 4)
    t[ty + i][tx] = in[(long)(r0 + ty + i) * C + c0 + tx];
  __syncthreads();
  #pragma unroll
  for (int i = 0; i < 64; i += 4)
    out[(long)(c0 + ty + i) * R + r0 + tx] = to_bf16(t[tx][ty + i]);
}

__global__ void concat2(const float* __restrict__ a, const float* __restrict__ b,
                        float* __restrict__ o, int n) {
  int i = blockIdx.x * 256 + threadIdx.x;
  if (i < n) o[i] = a[i];
  else if (i < 2 * n) o[i] = b[i - n];
}

// GROUP_M=4 swizzle: consecutive blocks cover 4 tm x (gridDim.x) tn.
__device__ __forceinline__ void swizzle_tiles(int& tm, int& tn) {
  int nx = gridDim.x;
  int lin = blockIdx.y * nx + blockIdx.x;
  int span = nx * 4;
  int group = lin / span;
  int ing = lin % span;
  tm = group * 4 + (ing & 3);
  tn = ing >> 2;
}

// ---------------- legacy 128x128 NT GEMM (kept for the V projection) --------
__global__ __launch_bounds__(256, 4) void gemm_nt(
    const u16* __restrict__ A, int lda,
    const u16* __restrict__ B, int ldb,
    u16* __restrict__ C1, u16* __restrict__ C2, int splitN, int ldc,
    int Kd, float scale,
    const float* __restrict__ bias, int biasMode)   // 0 none, 1 per-col, 2 per-row
{
  __shared__ u16 SM[2][8192];
  u16* As = SM[0];
  u16* Bs = SM[1];

  int tid = threadIdx.x;
  int wave = tid >> 6, lane = tid & 63;
  int quad = lane >> 4, ln = lane & 15;
  int wm = wave >> 1, wn = wave & 1;
  int tm, tn;
  swizzle_tiles(tm, tn);
  int c8 = lane >> 3, ml = lane & 7;

  const f32x4 fz = {0.f, 0.f, 0.f, 0.f};
  f32x4 acc[4][4];
  #pragma unroll
  for (int i = 0; i < 4; i++)
    #pragma unroll
    for (int j = 0; j < 4; j++) acc[i][j] = fz;

  const u16* Abase = A + (long)(tm * 128 + ml) * lda + c8 * 8;
  const u16* Bbase = B + (long)(tn * 128 + ml) * ldb + c8 * 8;

  for (int kt = 0; kt < Kd; kt += 64) {
    __syncthreads();
    #pragma unroll
    for (int i = 0; i < 4; i++) {
      int mg = wave * 4 + i;
      glds16(Abase + (long)mg * 8 * lda + kt, &As[mg * 512]);
      glds16(Bbase + (long)mg * 8 * ldb + kt, &Bs[mg * 512]);
    }
    __syncthreads();
    #pragma unroll
    for (int ks = 0; ks < 2; ks++) {
      bf16x8 af[4], bfr[4];
      int c = ks * 4 + quad;
      #pragma unroll
      for (int mt = 0; mt < 4; mt++) {
        int m = wm * 64 + mt * 16 + ln;
        af[mt] = *(const bf16x8*)&As[((m >> 3) * 64 + c * 8 + (m & 7)) * 8];
      }
      #pragma unroll
      for (int nt = 0; nt < 4; nt++) {
        int n = wn * 64 + nt * 16 + ln;
        bfr[nt] = *(const bf16x8*)&Bs[((n >> 3) * 64 + c * 8 + (n & 7)) * 8];
      }
      #pragma unroll
      for (int mt = 0; mt < 4; mt++)
        #pragma unroll
        for (int nt = 0; nt < 4; nt++)
          acc[mt][nt] = __builtin_amdgcn_mfma_f32_16x16x32_bf16(af[mt], bfr[nt], acc[mt][nt], 0, 0, 0);
    }
  }

  int rowBase = tm * 128 + wm * 64;
  int colBase = tn * 128 + wn * 64;
  u16* Cw = C1; int outCol = colBase;
  if (colBase >= splitN) { Cw = C2; outCol = colBase - splitN; }
  u16* eb = &SM[0][0] + wave * 4096;

  __syncthreads();
  #pragma unroll
  for (int mt = 0; mt < 4; mt++) {
    #pragma unroll
    for (int nt = 0; nt < 4; nt++) {
      int colL = nt * 16 + ln;
      float bcol = (biasMode == 1) ? bias[colBase + colL] : 0.f;
      #pragma unroll
      for (int r = 0; r < 4; r++) {
        int rowL = mt * 16 + quad * 4 + r;
        float brow = (biasMode == 2) ? bias[rowBase + rowL] : 0.f;
        float v = acc[mt][nt][r] * scale + bcol + brow;
        eb[rowL * 64 + (((colL >> 3) ^ (rowL & 7)) << 3) + (colL & 7)] = to_bf16(v);
      }
    }
  }
  {
    int row = lane;
    long gr = (long)(rowBase + row) * ldc + outCol;
    #pragma unroll
    for (int c = 0; c < 8; c++) {
      u16x8 ch = *(const u16x8*)&eb[row * 64 + ((c ^ (row & 7)) << 3)];
      *(u16x8*)&Cw[gr + c * 8] = ch;
    }
  }
}

// ---------------- 256x256 8-wave GEMM core: 1 barrier/K-tile, B triple-buf --
// LDS layout (u16 units): A0 @0, A1 @16384, B0 @32768, B1 @49152, B2 @65536.
__device__ __forceinline__ void gemm256_core(
    const u16* __restrict__ A, int lda,
    const u16* __restrict__ B, int ldb,
    int NT, int tm, int tn, u16* SMp, f32x4 (&acc)[8][4])
{
  int tid = threadIdx.x;
  int wave = tid >> 6, lane = tid & 63;
  int quad = lane >> 4, ln = lane & 15;
  int wm = wave >> 2, wn = wave & 3;
  int c8 = lane >> 3, ml = lane & 7;

  const f32x4 fz = {0.f, 0.f, 0.f, 0.f};
  #pragma unroll
  for (int i = 0; i < 8; i++)
    #pragma unroll
    for (int j = 0; j < 4; j++) acc[i][j] = fz;

  const u16* Ab = A + (long)(tm * 256 + ml) * lda + c8 * 8;
  const u16* Bb = B + (long)(tn * 256 + ml) * ldb + c8 * 8;

  // prologue: A(0)->A0, B(0)->B0, B(1)->B1; wait A(0),B(0); B(1) stays out.
  #pragma unroll
  for (int h = 0; h < 2; h++) {
    int hg = h * 16 + wave * 2;
    glds16(Ab + (long)(hg * 8) * lda,       SMp + hg * 512);
    glds16(Ab + (long)(hg * 8 + 8) * lda,   SMp + (hg + 1) * 512);
  }
  #pragma unroll
  for (int h = 0; h < 2; h++) {
    int hg = h * 16 + wave * 2;
    glds16(Bb + (long)(hg * 8) * ldb,       SMp + 32768 + hg * 512);
    glds16(Bb + (long)(hg * 8 + 8) * ldb,   SMp + 32768 + (hg + 1) * 512);
  }
  {
    int kt1 = (NT > 1) ? 64 : 0;
    #pragma unroll
    for (int h = 0; h < 2; h++) {
      int hg = h * 16 + wave * 2;
      glds16(Bb + (long)(hg * 8) * ldb + kt1,     SMp + 49152 + hg * 512);
      glds16(Bb + (long)(hg * 8 + 8) * ldb + kt1, SMp + 49152 + (hg + 1) * 512);
    }
  }
  asm volatile("s_waitcnt vmcnt(4)" ::: "memory");
  __builtin_amdgcn_s_barrier();
  __builtin_amdgcn_sched_barrier(0);

  int bcur = 0;   // B buffer holding tile t
  for (int t = 0; t < NT; t++) {
    const int p = t & 1;
    const u16* Ar = SMp + p * 16384;
    const u16* Br = SMp + 32768 + bcur * 16384;

    // ---- stage A(t+1) -> A[(t+1)&1], B(t+2) -> B[(bcur+2)%3] (issued first,
    //      full-tile landing window; tail clamped so counts stay uniform) ----
    {
      int ktA = ((t + 1 < NT) ? (t + 1) : (NT - 1)) << 6;
      u16* dA = SMp + ((t + 1) & 1) * 16384;
      #pragma unroll
      for (int h = 0; h < 2; h++) {
        int hg = h * 16 + wave * 2;
        glds16(Ab + (long)(hg * 8) * lda + ktA,     dA + hg * 512);
        glds16(Ab + (long)(hg * 8 + 8) * lda + ktA, dA + (hg + 1) * 512);
      }
      int ktB = ((t + 2 < NT) ? (t + 2) : (NT - 1)) << 6;
      int bst = bcur + 2; if (bst >= 3) bst -= 3;
      u16* dB = SMp + 32768 + bst * 16384;
      #pragma unroll
      for (int h = 0; h < 2; h++) {
        int hg = h * 16 + wave * 2;
        glds16(Bb + (long)(hg * 8) * ldb + ktB,     dB + hg * 512);
        glds16(Bb + (long)(hg * 8 + 8) * ldb + ktB, dB + (hg + 1) * 512);
      }
    }
    __builtin_amdgcn_sched_barrier(0);   // pin stage issue before frag reads

    // ---- fragment reads + MFMA: compiler-scheduled (fine lgkm interleave,
    //      waves free to desync until the tile-end barrier) ----
    bf16x8 bfr[2][4];
    #pragma unroll
    for (int nt = 0; nt < 4; nt++) {
      int n = wn * 64 + nt * 16 + ln;
      #pragma unroll
      for (int ks = 0; ks < 2; ks++)
        bfr[ks][nt] = *(const bf16x8*)(Br + ((n >> 3) * 64 + (ks * 4 + quad) * 8 + (n & 7)) * 8);
    }
    #pragma unroll
    for (int g = 0; g < 4; g++) {
      bf16x8 af[2][2];
      #pragma unroll
      for (int dm = 0; dm < 2; dm++) {
        int m = wm * 128 + (g * 2 + dm) * 16 + ln;
        #pragma unroll
        for (int ks = 0; ks < 2; ks++)
          af[dm][ks] = *(const bf16x8*)(Ar + ((m >> 3) * 64 + (ks * 4 + quad) * 8 + (m & 7)) * 8);
      }
      #pragma unroll
      for (int ks = 0; ks < 2; ks++)
        #pragma unroll
        for (int dm = 0; dm < 2; dm++)
          #pragma unroll
          for (int nt = 0; nt < 4; nt++)
            acc[g * 2 + dm][nt] = __builtin_amdgcn_mfma_f32_16x16x32_bf16(
                af[dm][ks], bfr[ks][nt], acc[g * 2 + dm][nt], 0, 0, 0);
    }

    asm volatile("s_waitcnt vmcnt(4)" ::: "memory");  // A(t+1),B(t+1) landed
    __builtin_amdgcn_s_barrier();
    __builtin_amdgcn_sched_barrier(0);
    bcur = (bcur == 2) ? 0 : bcur + 1;
  }
}

// ---------------- 256x256 NT GEMM with split outputs ----------------
__global__ __launch_bounds__(512, 2) void gemm_nt256(
    const u16* __restrict__ A, int lda,
    const u16* __restrict__ B, int ldb,
    u16* __restrict__ C1, u16* __restrict__ C2, int splitN, int ldc,
    int Kd, float scale,
    const float* __restrict__ bias, int biasMode)
{
  __shared__ u16 SM[5][16384];   // 160 KB: A dbuf + B tbuf
  int tm, tn;
  swizzle_tiles(tm, tn);
  f32x4 acc[8][4];
  gemm256_core(A, lda, B, ldb, Kd >> 6, tm, tn, &SM[0][0], acc);

  int tid = threadIdx.x;
  int wave = tid >> 6, lane = tid & 63;
  int quad = lane >> 4, ln = lane & 15;
  int wm = wave >> 2, wn = wave & 3;

  int rowBase = tm * 256 + wm * 128;
  int colBase = tn * 256 + wn * 64;
  u16* Cw = C1; int outCol = colBase;
  if (colBase >= splitN) { Cw = C2; outCol = colBase - splitN; }
  u16* eb = &SM[0][0] + wave * 8192;   // 128x64 u16, wave-private (SM[0..3])

  asm volatile("s_waitcnt vmcnt(0)" ::: "memory");   // tail stages landed
  __builtin_amdgcn_s_barrier();
  __builtin_amdgcn_sched_barrier(0);

  #pragma unroll
  for (int mt = 0; mt < 8; mt++) {
    #pragma unroll
    for (int nt = 0; nt < 4; nt++) {
      int colL = nt * 16 + ln;
      float bcol = (biasMode == 1) ? bias[colBase + colL] : 0.f;
      #pragma unroll
      for (int r = 0; r < 4; r++) {
        int rowL = mt * 16 + quad * 4 + r;
        float brow = (biasMode == 2) ? bias[rowBase + rowL] : 0.f;
        float v = acc[mt][nt][r] * scale + bcol + brow;
        eb[rowL * 64 + (((colL >> 3) ^ (rowL & 7)) << 3) + (colL & 7)] = to_bf16(v);
      }
    }
  }
  #pragma unroll
  for (int rr = 0; rr < 2; rr++) {
    int row = rr * 64 + lane;
    long gr = (long)(rowBase + row) * ldc + outCol;
    #pragma unroll
    for (int c = 0; c < 8; c++) {
      u16x8 ch = *(const u16x8*)&eb[row * 64 + ((c ^ (row & 7)) << 3)];
      *(u16x8*)&Cw[gr + c * 8] = ch;
    }
  }
}

// ---------------- 256x256 S GEMM storing E=exp(S) + sum partials ------------
__global__ __launch_bounds__(512, 2) void gemm_s256(
    const u16* __restrict__ Q, const u16* __restrict__ K,
    u16* __restrict__ E1, u16* __restrict__ E2,
    float* __restrict__ statsP, float scale)
{
  __shared__ u16 SM[5][16384];   // 160 KB
  int bz = blockIdx.z >> 1, half = blockIdx.z & 1;
  const u16* A = Q + (long)bz * 2097152 + half * 512;
  const u16* B = K + (long)bz * 2097152 + half * 512;
  u16* Ed = (half ? E2 : E1) + (long)bz * 4194304;
  statsP += (long)blockIdx.z * 65536;   // [b][h][row][kb]

  int tm, tn;
  swizzle_tiles(tm, tn);
  f32x4 acc[8][4];
  gemm256_core(A, 1024, B, 1024, 8 /* 512/64 */, tm, tn, &SM[0][0], acc);

  int tid = threadIdx.x;
  int wave = tid >> 6, lane = tid & 63;
  int quad = lane >> 4, ln = lane & 15;
  int wm = wave >> 2, wn = wave & 3;

  int rowBase = tm * 256 + wm * 128;
  int colBase = tn * 256 + wn * 64;
  int kb = tn * 4 + wn;                 // 64-col block index (0..31)
  u16* eb = &SM[0][0] + wave * 8192;

  asm volatile("s_waitcnt vmcnt(0)" ::: "memory");
  __builtin_amdgcn_s_barrier();
  __builtin_amdgcn_sched_barrier(0);

  #pragma unroll
  for (int mt = 0; mt < 8; mt++) {
    #pragma unroll
    for (int nt = 0; nt < 4; nt++) {
      int colL = nt * 16 + ln;
      #pragma unroll
      for (int r = 0; r < 4; r++) {
        int rowL = mt * 16 + quad * 4 + r;
        eb[rowL * 64 + (((colL >> 3) ^ (rowL & 7)) << 3) + (colL & 7)] =
            to_bf16(__expf(acc[mt][nt][r] * scale));
      }
    }
  }
  #pragma unroll
  for (int rr = 0; rr < 2; rr++) {
    int row = rr * 64 + lane;
    u16x8 ch[8];
    #pragma unroll
    for (int c = 0; c < 8; c++)
      ch[c] = *(const u16x8*)&eb[row * 64 + ((c ^ (row & 7)) << 3)];
    u16* Ep = Ed + (long)(rowBase + row) * 2048 + colBase;
    #pragma unroll
    for (int c = 0; c < 8; c++)
      *(u16x8*)&Ep[c * 8] = ch[c];
    float L = 0.f;
    #pragma unroll
    for (int c = 0; c < 8; c++)
      #pragma unroll
      for (int j = 0; j < 8; j++) L += b2f(ch[c][j]);
    statsP[(rowBase + row) * 32 + kb] = L;
  }
}

// ---------------- stats reduce: 32 partials -> inv-denominator ----------------
__global__ void stats_reduce(const float* __restrict__ sp, float* __restrict__ so,
                             const float* __restrict__ lamPtr) {
  int gid = blockIdx.x * 256 + threadIdx.x;   // 0..32767
  const float* p = sp + (long)gid * 32;
  float L = 0.f;
  #pragma unroll
  for (int kb = 0; kb < 32; kb++) L += p[kb];
  int half = (gid >> 11) & 1;
  so[gid] = (half ? lamPtr[0] : 1.0f) / L;
}

// ---------------- apply: O = (E1*i1 - E2*i2) @ V ----------------
// (verified round-10 version, unchanged)
__global__ __launch_bounds__(512, 2) void apply_pv(
    const u16* __restrict__ E1, const u16* __restrict__ E2,
    const u16* __restrict__ VT, const float* __restrict__ inv,
    float* __restrict__ Out)
{
  __shared__ u16 Vs[2][32768];    // 2 x [512 d][64 k] packed subtile, 128 KB
  __shared__ u16 Pb[2][4096];     // 2 x [64 q][64 k] packed subtile, 16 KB
  __shared__ float i1s[64], i2s[64];

  const int NT = 32;
  int b = blockIdx.x & 7, qt = blockIdx.x >> 3;
  int q0 = qt * 64;
  int tid = threadIdx.x;
  int wave = tid >> 6, lane = tid & 63, quad = lane >> 4, ln = lane & 15;
  int c8 = lane >> 3, ml = lane & 7;
  int r = tid >> 3, cg8 = tid & 7;            // P producer mapping: 64 rows x 8 col-groups

  const u16* e1p = E1 + ((long)b * 2048 + q0 + r) * 2048 + cg8 * 8;
  const u16* e2p = E2 + ((long)b * 2048 + q0 + r) * 2048 + cg8 * 8;
  const u16* Vbase = VT + (long)b * 2048;     // row stride 16384 (u16)
  int pw = (r >> 3) * 512 + cg8 * 64 + (r & 7) * 8;   // packed P write idx (u16)

  const f32x4 fz = {0.f, 0.f, 0.f, 0.f};
  f32x4 acc[4][4];
  #pragma unroll
  for (int i = 0; i < 4; i++)
    #pragma unroll
    for (int j = 0; j < 4; j++) acc[i][j] = fz;

  // ---- prologue ----
  if (tid < 64)       i1s[tid]       = inv[(long)(b * 2 + 0) * 2048 + q0 + tid];
  else if (tid < 128) i2s[tid - 64]  = inv[(long)(b * 2 + 1) * 2048 + q0 + (tid - 64)];
  u16x8 a1 = *(const u16x8*)(e1p);            // E(0), compiler-tracked
  u16x8 a2 = *(const u16x8*)(e2p);
  __builtin_amdgcn_sched_barrier(0);
  #pragma unroll
  for (int i = 0; i < 8; i++) {               // V(0) -> Vs[0]
    int dg = wave * 8 + i;
    glds16(Vbase + (long)(dg * 8 + ml) * 16384 + c8 * 8, &Vs[0][dg * 512]);
  }
  __builtin_amdgcn_sched_barrier(0);
  asm volatile("s_waitcnt lgkmcnt(0)" ::: "memory");   // i1s/i2s stores done
  __builtin_amdgcn_s_barrier();                        // i1s visible
  __builtin_amdgcn_sched_barrier(0);
  float i1 = i1s[r], i2 = i2s[r];
  {
    u16x8 o;
    #pragma unroll
    for (int j = 0; j < 8; j++)
      o[j] = to_bf16(b2f(a1[j]) * i1 - b2f(a2[j]) * i2);
    *(u16x8*)&Pb[0][pw] = o;                  // P(0)
  }
  a1 = *(const u16x8*)(e1p + 64);             // E(1)
  a2 = *(const u16x8*)(e2p + 64);
  __builtin_amdgcn_sched_barrier(0);
  asm volatile("s_waitcnt lgkmcnt(0)" ::: "memory");   // P(0) write done
  asm volatile("s_waitcnt vmcnt(2)" ::: "memory");     // V(0) landed, E(1) flying
  __builtin_amdgcn_sched_barrier(0);
  __builtin_amdgcn_s_barrier();
  __builtin_amdgcn_sched_barrier(0);

  // ---- main loop ----
  for (int t = 0; t < NT; t++) {
    const int p = t & 1;
    const u16* Vr = &Vs[p][0];
    const u16* Pr = &Pb[p][0];
    u16* Vw = &Vs[p ^ 1][0];
    u16* Pw = &Pb[p ^ 1][0];
    int ktv = ((t + 1 < NT) ? (t + 1) : (NT - 1)) << 6;   // V(t+1)
    int kte = ((t + 2 < NT) ? (t + 2) : (NT - 1)) << 6;   // E(t+2)
    bf16x8 vf[2][4];

    #pragma unroll
    for (int q = 0; q < 4; q++) {
      bf16x8 pf[2];
      #pragma unroll
      for (int ks = 0; ks < 2; ks++) {
        int m = q * 16 + ln;
        pf[ks] = *(const bf16x8*)&Pr[((m >> 3) * 64 + (ks * 4 + quad) * 8 + (m & 7)) * 8];
      }
      if (q == 0) {
        #pragma unroll
        for (int ks = 0; ks < 2; ks++)
          #pragma unroll
          for (int nt = 0; nt < 4; nt++) {
            int d = wave * 64 + nt * 16 + ln;
            vf[ks][nt] = *(const bf16x8*)&Vr[((d >> 3) * 64 + (ks * 4 + quad) * 8 + (d & 7)) * 8];
          }
      }
      // stage V(t+1): 2 glds16 per wave per phase
      #pragma unroll
      for (int i = 0; i < 2; i++) {
        int dg = wave * 8 + q * 2 + i;
        glds16(Vbase + (long)(dg * 8 + ml) * 16384 + ktv + c8 * 8, Vw + dg * 512);
      }
      if (q == 3) {
        __builtin_amdgcn_sched_barrier(0);
        // compiler inserts the wait for a1/a2 (E(t+1)) here; V(t+1)x8 stay out
        u16x8 o;
        #pragma unroll
        for (int j = 0; j < 8; j++)
          o[j] = to_bf16(b2f(a1[j]) * i1 - b2f(a2[j]) * i2);
        *(u16x8*)&Pw[pw] = o;                             // P(t+1)
        a1 = *(const u16x8*)(e1p + kte);                  // E(t+2)
        a2 = *(const u16x8*)(e2p + kte);
      }
      __builtin_amdgcn_sched_barrier(0);
      __builtin_amdgcn_s_barrier();
      asm volatile("s_waitcnt lgkmcnt(0)" ::: "memory");
      __builtin_amdgcn_sched_barrier(0);
      __builtin_amdgcn_s_setprio(1);
      #pragma unroll
      for (int ks = 0; ks < 2; ks++)
        #pragma unroll
        for (int nt = 0; nt < 4; nt++)
          acc[q][nt] = __builtin_amdgcn_mfma_f32_16x16x32_bf16(pf[ks], vf[ks][nt], acc[q][nt], 0, 0, 0);
      __builtin_amdgcn_s_setprio(0);
      __builtin_amdgcn_sched_barrier(0);
      if (q == 3) asm volatile("s_waitcnt vmcnt(2)" ::: "memory");  // V(t+1) landed
      __builtin_amdgcn_s_barrier();
      __builtin_amdgcn_sched_barrier(0);
    }
  }

  #pragma unroll
  for (int mt = 0; mt < 4; mt++)
    #pragma unroll
    for (int nt = 0; nt < 4; nt++)
      #pragma unroll
      for (int r2 = 0; r2 < 4; r2++)
        Out[((long)b * 2048 + q0 + mt * 16 + quad * 4 + r2) * 512 + wave * 64 + nt * 16 + ln] =
            acc[mt][nt][r2];
}

// ---------------- launch ----------------

extern "C" void kernel_launch(void* const* d_in, const int* in_sizes, int n_in,
                              void* d_out, int out_size, void* d_ws, size_t ws_size,
                              hipStream_t stream)
{
  const float* X   = (const float*)d_in[0];
  const float* lam = (const float*)d_in[1];
  const float* Wq  = (const float*)d_in[2];
  const float* bq  = (const float*)d_in[3];
  const float* Wk  = (const float*)d_in[4];
  const float* bk  = (const float*)d_in[5];
  const float* Wv  = (const float*)d_in[6];
  const float* bv  = (const float*)d_in[7];
  float* Out = (float*)d_out;
  char* ws = (char*)d_ws;

  u16*  WqkT   = (u16*)(ws + 0);           //  4 MB [2048][1024]
  u16*  WvT    = (u16*)(ws + 4194304);     //  1 MB [512][1024]
  float* bqk   = (float*)(ws + 5242880);   //  8 KB [2048]
  u16*  Qb     = (u16*)(ws + 6291456);     // 32 MB [16384][1024]
  u16*  Kb     = (u16*)(ws + 39845888);    // 32 MB [16384][1024]
  u16*  VTb    = (u16*)(ws + 73400320);    // 16 MB [512][16384]
  u16*  Xb     = (u16*)(ws + 90177536);    // 32 MB [16384][1024]
  u16*  E1     = (u16*)(ws + 90177536);    // 64 MB, overlaps Xb (Xb dead first)
  u16*  E2     = (u16*)(ws + 157286400);   // 64 MB
  float* statsP= (float*)(ws + 224395264); //  4 MB [8][2][2048][32]
  float* invD  = (float*)(ws + 228589568); // 128 KB [8][2][2048]

  cvt_x<<<16384, 256, 0, stream>>>((const float4*)X, (u16x4*)Xb, 4194304);
  transpose_cvt<<<dim3(16, 16), dim3(64, 4), 0, stream>>>(Wq, WqkT, 1024, 1024);
  transpose_cvt<<<dim3(16, 16), dim3(64, 4), 0, stream>>>(Wk, WqkT + 1024 * 1024, 1024, 1024);
  transpose_cvt<<<dim3(8, 16),  dim3(64, 4), 0, stream>>>(Wv, WvT, 1024, 512);
  concat2<<<8, 256, 0, stream>>>(bq, bk, bqk, 1024);

  // [Q|K] = Xb @ WqkT^T + bqk, split into Qb (cols<1024) and Kb  (256^2 tiles)
  gemm_nt256<<<dim3(8, 64), 512, 0, stream>>>(Xb, 1024, WqkT, 1024,
                                              Qb, Kb, 1024, 1024,
                                              1024, 1.0f, bqk, 1);
  // V^T[d][m] = sum_e WvT[d][e]*Xb[m][e] + bv[d]  (legacy 128^2 kernel)
  gemm_nt<<<dim3(128, 4), 256, 0, stream>>>(WvT, 1024, Xb, 1024,
                                            VTb, VTb, 1 << 30, 16384,
                                            1024, 1.0f, bv, 2);

  const float s = 0.044194173824159216f;  // 1/sqrt(512)
  gemm_s256<<<dim3(8, 8, 16), 512, 0, stream>>>(Qb, Kb, E1, E2, statsP, s);

  stats_reduce<<<128, 256, 0, stream>>>(statsP, invD, lam);
  apply_pv<<<256, 512, 0, stream>>>(E1, E2, VTb, invD, Out);
}

// Round 6
// 474.925 us; speedup vs baseline: 1.0085x; 1.0085x over previous
//
#include <hip/hip_runtime.h>

// DiffAttn on MI355X, round 13.
// Rounds 10-12: three different K-loop schedules identical (141/140/141us,
// MfmaUtil 20%) -> schedule falsified. Model: per-BLOCK overhead P (cold
// pipeline fill + exp/transpose/store epilogue + drain) ~ tens of
// tile-equivalents (calibrated from m201: 62% util at 128 tiles/block);
// at 8 K-tiles/block util is doomed to ~20% regardless of schedule.
// Fix: PERSISTENT blocks. gemm_s256p: one block = 4 output tiles (same tn,
// consecutive tm), 64 BK=32 K-tiles in ONE continuous counted-vmcnt pipeline.
// Epilogue runs inside the pipeline with NO drain: BK=32 shrinks the
// pipeline to 80 KB (A dbuf 2x16K + B tbuf 3x16K) leaving a disjoint 64 KB
// wave-private epilogue buffer (no barriers, vmem counters untouched).
// Ledger/tile: issue A(t+1)x2 + B(t+2)x2, end vmcnt(2); rolls across sub
// boundaries; clamped tail re-stages identical bytes (benign); vmcnt(0)
// once before endpgm. gemm_nt256p: same, SUBS=2, 64 tiles/block, 256 blocks.
// apply_pv / legacy V-GEMM / conversions unchanged (verified).

typedef unsigned short u16;
typedef short    bf16x8 __attribute__((ext_vector_type(8)));
typedef unsigned short u16x8 __attribute__((ext_vector_type(8)));
typedef unsigned short u16x4 __attribute__((ext_vector_type(4)));
typedef float    f32x4  __attribute__((ext_vector_type(4)));

typedef __attribute__((address_space(3))) unsigned int       lds_uint;
typedef __attribute__((address_space(1))) const unsigned int gl_uint;

__device__ __forceinline__ void glds16(const void* g, void* l) {
  __builtin_amdgcn_global_load_lds((gl_uint*)g, (lds_uint*)l, 16, 0, 0);
}

__device__ __forceinline__ u16 to_bf16(float f) {
  unsigned u = __float_as_uint(f);
  return (u16)((u + 0x7FFFu + ((u >> 16) & 1u)) >> 16);  // RNE
}
__device__ __forceinline__ float b2f(u16 h) {
  return __uint_as_float(((unsigned)h) << 16);
}

// ---------------- conversion kernels ----------------

__global__ void cvt_x(const float4* __restrict__ in, u16x4* __restrict__ out, int n4) {
  int i = blockIdx.x * 256 + threadIdx.x;
  if (i >= n4) return;
  float4 v = in[i];
  u16x4 o;
  o[0] = to_bf16(v.x); o[1] = to_bf16(v.y); o[2] = to_bf16(v.z); o[3] = to_bf16(v.w);
  out[i] = o;
}

__global__ void transpose_cvt(const float* __restrict__ in, u16* __restrict__ out,
                              int R, int C) {
  __shared__ float t[64][65];
  int c0 = blockIdx.x * 64, r0 = blockIdx.y * 64;
  int tx = threadIdx.x, ty = threadIdx.y;
  #pragma unroll
  for (int i = 0; i < 64; i += 4)
    t[ty + i][tx] = in[(long)(r0 + ty + i) * C + c0 + tx];
  __syncthreads();
  #pragma unroll
  for (int i = 0; i < 64; i += 4)
    out[(long)(c0 + ty + i) * R + r0 + tx] = to_bf16(t[tx][ty + i]);
}

__global__ void concat2(const float* __restrict__ a, const float* __restrict__ b,
                        float* __restrict__ o, int n) {
  int i = blockIdx.x * 256 + threadIdx.x;
  if (i < n) o[i] = a[i];
  else if (i < 2 * n) o[i] = b[i - n];
}

// GROUP_M=4 swizzle (legacy gemm_nt only).
__device__ __forceinline__ void swizzle_tiles(int& tm, int& tn) {
  int nx = gridDim.x;
  int lin = blockIdx.y * nx + blockIdx.x;
  int span = nx * 4;
  int group = lin / span;
  int ing = lin % span;
  tm = group * 4 + (ing & 3);
  tn = ing >> 2;
}

// ---------------- legacy 128x128 NT GEMM (kept for the V projection) --------
__global__ __launch_bounds__(256, 4) void gemm_nt(
    const u16* __restrict__ A, int lda,
    const u16* __restrict__ B, int ldb,
    u16* __restrict__ C1, u16* __restrict__ C2, int splitN, int ldc,
    int Kd, float scale,
    const float* __restrict__ bias, int biasMode)   // 0 none, 1 per-col, 2 per-row
{
  __shared__ u16 SM[2][8192];
  u16* As = SM[0];
  u16* Bs = SM[1];

  int tid = threadIdx.x;
  int wave = tid >> 6, lane = tid & 63;
  int quad = lane >> 4, ln = lane & 15;
  int wm = wave >> 1, wn = wave & 1;
  int tm, tn;
  swizzle_tiles(tm, tn);
  int c8 = lane >> 3, ml = lane & 7;

  const f32x4 fz = {0.f, 0.f, 0.f, 0.f};
  f32x4 acc[4][4];
  #pragma unroll
  for (int i = 0; i < 4; i++)
    #pragma unroll
    for (int j = 0; j < 4; j++) acc[i][j] = fz;

  const u16* Abase = A + (long)(tm * 128 + ml) * lda + c8 * 8;
  const u16* Bbase = B + (long)(tn * 128 + ml) * ldb + c8 * 8;

  for (int kt = 0; kt < Kd; kt += 64) {
    __syncthreads();
    #pragma unroll
    for (int i = 0; i < 4; i++) {
      int mg = wave * 4 + i;
      glds16(Abase + (long)mg * 8 * lda + kt, &As[mg * 512]);
      glds16(Bbase + (long)mg * 8 * ldb + kt, &Bs[mg * 512]);
    }
    __syncthreads();
    #pragma unroll
    for (int ks = 0; ks < 2; ks++) {
      bf16x8 af[4], bfr[4];
      int c = ks * 4 + quad;
      #pragma unroll
      for (int mt = 0; mt < 4; mt++) {
        int m = wm * 64 + mt * 16 + ln;
        af[mt] = *(const bf16x8*)&As[((m >> 3) * 64 + c * 8 + (m & 7)) * 8];
      }
      #pragma unroll
      for (int nt = 0; nt < 4; nt++) {
        int n = wn * 64 + nt * 16 + ln;
        bfr[nt] = *(const bf16x8*)&Bs[((n >> 3) * 64 + c * 8 + (n & 7)) * 8];
      }
      #pragma unroll
      for (int mt = 0; mt < 4; mt++)
        #pragma unroll
        for (int nt = 0; nt < 4; nt++)
          acc[mt][nt] = __builtin_amdgcn_mfma_f32_16x16x32_bf16(af[mt], bfr[nt], acc[mt][nt], 0, 0, 0);
    }
  }

  int rowBase = tm * 128 + wm * 64;
  int colBase = tn * 128 + wn * 64;
  u16* Cw = C1; int outCol = colBase;
  if (colBase >= splitN) { Cw = C2; outCol = colBase - splitN; }
  u16* eb = &SM[0][0] + wave * 4096;

  __syncthreads();
  #pragma unroll
  for (int mt = 0; mt < 4; mt++) {
    #pragma unroll
    for (int nt = 0; nt < 4; nt++) {
      int colL = nt * 16 + ln;
      float bcol = (biasMode == 1) ? bias[colBase + colL] : 0.f;
      #pragma unroll
      for (int r = 0; r < 4; r++) {
        int rowL = mt * 16 + quad * 4 + r;
        float brow = (biasMode == 2) ? bias[rowBase + rowL] : 0.f;
        float v = acc[mt][nt][r] * scale + bcol + brow;
        eb[rowL * 64 + (((colL >> 3) ^ (rowL & 7)) << 3) + (colL & 7)] = to_bf16(v);
      }
    }
  }
  {
    int row = lane;
    long gr = (long)(rowBase + row) * ldc + outCol;
    #pragma unroll
    for (int c = 0; c < 8; c++) {
      u16x8 ch = *(const u16x8*)&eb[row * 64 + ((c ^ (row & 7)) << 3)];
      *(u16x8*)&Cw[gr + c * 8] = ch;
    }
  }
}

// ======================= persistent 256-wide GEMM kernels =====================
// Shared geometry: 256(M)x256(N) output tiles, 8 waves (2m x 4n), per-wave
// 128x64 acc[8][4]. BK=32. LDS (u16 idx): A dbuf @0/@8192, B tbuf
// @16384+{0,1,2}*8192, epilogue eb @40960 + wave*4096 (64 rows x 64 cols).
// Staging lane map (16 rows x 4 colgroups per glds16):
//   dr = (lane>>5)*8 + (lane&7), cg = (lane>>3)&3; LDS packed layout
//   elem(row,col) -> (row>>3)*256 + (col>>3)*64 + (row&7)*8 + (col&7)  [u16]
//   == lane-linear dest (proof: lane*8 decomposition), so glds16 fits.
// Fragment read (row m, k-group quad): b128 @ ((m>>3)*32 + quad*8 + (m&7))*8.

// ---------------- persistent S GEMM: E=exp(S) + per-64col sum partials -------
// Block = 4 output tiles (tm = tmg*4+sub, tn fixed), 64 K-tiles continuous.
__global__ __launch_bounds__(512, 2) void gemm_s256p(
    const u16* __restrict__ Q, const u16* __restrict__ K,
    u16* __restrict__ E1, u16* __restrict__ E2,
    float* __restrict__ statsP, float scale)
{
  __shared__ u16 SM[73728];   // 144 KB

  int bz = blockIdx.z >> 1, half = blockIdx.z & 1;
  const u16* A = Q + (long)bz * 2097152 + half * 512;
  const u16* B = K + (long)bz * 2097152 + half * 512;
  u16* Ed = (half ? E2 : E1) + (long)bz * 4194304;
  float* sp = statsP + (long)blockIdx.z * 65536;

  int tn = blockIdx.x;       // 0..7
  int tmg = blockIdx.y;      // 0..1
  int tid = threadIdx.x;
  int wave = tid >> 6, lane = tid & 63, quad = lane >> 4, ln = lane & 15;
  int wm = wave >> 2, wn = wave & 3;
  int dr = ((lane >> 5) << 3) + (lane & 7);
  int cg = (lane >> 3) & 3;

  const f32x4 fz = {0.f, 0.f, 0.f, 0.f};
  f32x4 acc[8][4];
  #pragma unroll
  for (int i = 0; i < 8; i++)
    #pragma unroll
    for (int j = 0; j < 4; j++) acc[i][j] = fz;

  // staging bases (per-thread): add (sub*256 + i*16)*1024 + kt for A chunk i.
  const u16* Abase = A + (long)(tmg * 1024 + wave * 32 + dr) * 1024 + cg * 8;
  const u16* Bbase = B + (long)(tn * 256 + wave * 32 + dr) * 1024 + cg * 8;
  u16* ldsA0 = SM;               // + (T&1)*8192, per-wave dst +wave*1024
  u16* ldsB0 = SM + 16384;       // + (T%3)*8192
  u16* eb = SM + 40960 + wave * 4096;

  // ---- prologue: A(0), B(0), B(1); wait A(0)+B(0); B(1) stays in flight ----
  glds16(Abase,                ldsA0 + wave * 1024);
  glds16(Abase + 16 * 1024,    ldsA0 + wave * 1024 + 512);
  glds16(Bbase,                ldsB0 + wave * 1024);
  glds16(Bbase + 16 * 1024,    ldsB0 + wave * 1024 + 512);
  glds16(Bbase + 32,           ldsB0 + 8192 + wave * 1024);
  glds16(Bbase + 16 * 1024 + 32, ldsB0 + 8192 + wave * 1024 + 512);
  asm volatile("s_waitcnt vmcnt(2)" ::: "memory");
  __builtin_amdgcn_s_barrier();
  __builtin_amdgcn_sched_barrier(0);

  for (int T = 0; T < 64; T++) {
    const u16* Ar = ldsA0 + (T & 1) * 8192;
    const u16* Br = ldsB0 + (T % 3) * 8192;

    // ---- stage A(T+1), B(T+2) (clamped tail re-stages identical bytes) ----
    {
      int Ta = (T + 1 < 64) ? T + 1 : 63;
      long roff = (long)((Ta >> 4) * 256) * 1024 + ((Ta & 15) << 5);
      u16* dA = ldsA0 + (Ta & 1) * 8192 + wave * 1024;
      glds16(Abase + roff,             dA);
      glds16(Abase + roff + 16 * 1024, dA + 512);
      int Tb = (T + 2 < 64) ? T + 2 : 63;
      int ktB = (Tb & 15) << 5;
      u16* dB = ldsB0 + (Tb % 3) * 8192 + wave * 1024;
      glds16(Bbase + ktB,             dB);
      glds16(Bbase + ktB + 16 * 1024, dB + 512);
    }
    __builtin_amdgcn_sched_barrier(0);

    // ---- fragments + 32 MFMA (compiler-scheduled lgkm interleave) ----
    bf16x8 bfr[4];
    #pragma unroll
    for (int nt = 0; nt < 4; nt++) {
      int n = wn * 64 + nt * 16 + ln;
      bfr[nt] = *(const bf16x8*)(Br + ((n >> 3) * 32 + quad * 8 + (n & 7)) * 8);
    }
    #pragma unroll
    for (int g = 0; g < 8; g++) {
      int m = wm * 128 + g * 16 + ln;
      bf16x8 af = *(const bf16x8*)(Ar + ((m >> 3) * 32 + quad * 8 + (m & 7)) * 8);
      #pragma unroll
      for (int nt = 0; nt < 4; nt++)
        acc[g][nt] = __builtin_amdgcn_mfma_f32_16x16x32_bf16(af, bfr[nt], acc[g][nt], 0, 0, 0);
    }

    asm volatile("s_waitcnt vmcnt(2)" ::: "memory");  // A(T+1),B(T+1) landed
    __builtin_amdgcn_s_barrier();
    __builtin_amdgcn_sched_barrier(0);

    // ---- in-pipeline epilogue at each sub boundary (wave-private eb,
    //      disjoint from A/B buffers: no drain, no barriers) ----
    if ((T & 15) == 15) {
      int sub = T >> 4;
      int rowBaseW = (tmg * 4 + sub) * 256 + wm * 128;
      int colBase = tn * 256 + wn * 64;
      int kb = tn * 4 + wn;
      #pragma unroll
      for (int h = 0; h < 2; h++) {
        #pragma unroll
        for (int mt = 0; mt < 4; mt++) {
          #pragma unroll
          for (int nt = 0; nt < 4; nt++) {
            int colL = nt * 16 + ln;
            #pragma unroll
            for (int r = 0; r < 4; r++) {
              int rowL = mt * 16 + quad * 4 + r;
              eb[rowL * 64 + (((colL >> 3) ^ (rowL & 7)) << 3) + (colL & 7)] =
                  to_bf16(__expf(acc[h * 4 + mt][nt][r] * scale));
            }
          }
        }
        // wave-private lockstep readback: store + row sum
        {
          int row = lane;
          u16x8 ch[8];
          #pragma unroll
          for (int c = 0; c < 8; c++)
            ch[c] = *(const u16x8*)&eb[row * 64 + ((c ^ (row & 7)) << 3)];
          u16* Ep = Ed + (long)(rowBaseW + h * 64 + row) * 2048 + colBase;
          #pragma unroll
          for (int c = 0; c < 8; c++)
            *(u16x8*)&Ep[c * 8] = ch[c];
          float L = 0.f;
          #pragma unroll
          for (int c = 0; c < 8; c++)
            #pragma unroll
            for (int j = 0; j < 8; j++) L += b2f(ch[c][j]);
          sp[(rowBaseW + h * 64 + row) * 32 + kb] = L;
        }
      }
      #pragma unroll
      for (int i = 0; i < 8; i++)
        #pragma unroll
        for (int j = 0; j < 4; j++) acc[i][j] = fz;
    }
  }
  // drain DMA before LDS deallocation
  asm volatile("s_waitcnt vmcnt(0)" ::: "memory");
}

// ---------------- persistent NT GEMM for the QK projection -------------------
// Block = 2 output tiles (tm = tmg*2+sub), K=1024 -> 64 K-tiles continuous.
__global__ __launch_bounds__(512, 2) void gemm_nt256p(
    const u16* __restrict__ A, const u16* __restrict__ B,
    u16* __restrict__ C1, u16* __restrict__ C2, int splitN, int ldc,
    float scale, const float* __restrict__ bias, int biasMode)
{
  __shared__ u16 SM[73728];   // 144 KB

  int tn = blockIdx.x;       // 0..7
  int tmg = blockIdx.y;      // 0..31
  int tid = threadIdx.x;
  int wave = tid >> 6, lane = tid & 63, quad = lane >> 4, ln = lane & 15;
  int wm = wave >> 2, wn = wave & 3;
  int dr = ((lane >> 5) << 3) + (lane & 7);
  int cg = (lane >> 3) & 3;

  const f32x4 fz = {0.f, 0.f, 0.f, 0.f};
  f32x4 acc[8][4];
  #pragma unroll
  for (int i = 0; i < 8; i++)
    #pragma unroll
    for (int j = 0; j < 4; j++) acc[i][j] = fz;

  const u16* Abase = A + (long)(tmg * 512 + wave * 32 + dr) * 1024 + cg * 8;
  const u16* Bbase = B + (long)(tn * 256 + wave * 32 + dr) * 1024 + cg * 8;
  u16* ldsA0 = SM;
  u16* ldsB0 = SM + 16384;
  u16* eb = SM + 40960 + wave * 4096;

  glds16(Abase,                  ldsA0 + wave * 1024);
  glds16(Abase + 16 * 1024,      ldsA0 + wave * 1024 + 512);
  glds16(Bbase,                  ldsB0 + wave * 1024);
  glds16(Bbase + 16 * 1024,      ldsB0 + wave * 1024 + 512);
  glds16(Bbase + 32,             ldsB0 + 8192 + wave * 1024);
  glds16(Bbase + 16 * 1024 + 32, ldsB0 + 8192 + wave * 1024 + 512);
  asm volatile("s_waitcnt vmcnt(2)" ::: "memory");
  __builtin_amdgcn_s_barrier();
  __builtin_amdgcn_sched_barrier(0);

  for (int T = 0; T < 64; T++) {
    const u16* Ar = ldsA0 + (T & 1) * 8192;
    const u16* Br = ldsB0 + (T % 3) * 8192;

    {
      int Ta = (T + 1 < 64) ? T + 1 : 63;
      long roff = (long)((Ta >> 5) * 256) * 1024 + ((Ta & 31) << 5);
      u16* dA = ldsA0 + (Ta & 1) * 8192 + wave * 1024;
      glds16(Abase + roff,             dA);
      glds16(Abase + roff + 16 * 1024, dA + 512);
      int Tb = (T + 2 < 64) ? T + 2 : 63;
      int ktB = (Tb & 31) << 5;
      u16* dB = ldsB0 + (Tb % 3) * 8192 + wave * 1024;
      glds16(Bbase + ktB,             dB);
      glds16(Bbase + ktB + 16 * 1024, dB + 512);
    }
    __builtin_amdgcn_sched_barrier(0);

    bf16x8 bfr[4];
    #pragma unroll
    for (int nt = 0; nt < 4; nt++) {
      int n = wn * 64 + nt * 16 + ln;
      bfr[nt] = *(const bf16x8*)(Br + ((n >> 3) * 32 + quad * 8 + (n & 7)) * 8);
    }
    #pragma unroll
    for (int g = 0; g < 8; g++) {
      int m = wm * 128 + g * 16 + ln;
      bf16x8 af = *(const bf16x8*)(Ar + ((m >> 3) * 32 + quad * 8 + (m & 7)) * 8);
      #pragma unroll
      for (int nt = 0; nt < 4; nt++)
        acc[g][nt] = __builtin_amdgcn_mfma_f32_16x16x32_bf16(af, bfr[nt], acc[g][nt], 0, 0, 0);
    }

    asm volatile("s_waitcnt vmcnt(2)" ::: "memory");
    __builtin_amdgcn_s_barrier();
    __builtin_amdgcn_sched_barrier(0);

    if ((T & 31) == 31) {
      int sub = T >> 5;
      int rowBaseW = (tmg * 2 + sub) * 256 + wm * 128;
      int colBase = tn * 256 + wn * 64;
      u16* Cw = C1; int outCol = colBase;
      if (colBase >= splitN) { Cw = C2; outCol = colBase - splitN; }
      #pragma unroll
      for (int h = 0; h < 2; h++) {
        #pragma unroll
        for (int mt = 0; mt < 4; mt++) {
          #pragma unroll
          for (int nt = 0; nt < 4; nt++) {
            int colL = nt * 16 + ln;
            float bcol = (biasMode == 1) ? bias[colBase + colL] : 0.f;
            #pragma unroll
            for (int r = 0; r < 4; r++) {
              int rowL = mt * 16 + quad * 4 + r;
              float brow = (biasMode == 2) ? bias[rowBaseW + h * 64 + rowL] : 0.f;
              float v = acc[h * 4 + mt][nt][r] * scale + bcol + brow;
              eb[rowL * 64 + (((colL >> 3) ^ (rowL & 7)) << 3) + (colL & 7)] = to_bf16(v);
            }
          }
        }
        {
          int row = lane;
          long gr = (long)(rowBaseW + h * 64 + row) * ldc + outCol;
          #pragma unroll
          for (int c = 0; c < 8; c++) {
            u16x8 ch = *(const u16x8*)&eb[row * 64 + ((c ^ (row & 7)) << 3)];
            *(u16x8*)&Cw[gr + c * 8] = ch;
          }
        }
      }
      #pragma unroll
      for (int i = 0; i < 8; i++)
        #pragma unroll
        for (int j = 0; j < 4; j++) acc[i][j] = fz;
    }
  }
  asm volatile("s_waitcnt vmcnt(0)" ::: "memory");
}

// ---------------- stats reduce: 32 partials -> inv-denominator ----------------
__global__ void stats_reduce(const float* __restrict__ sp, float* __restrict__ so,
                             const float* __restrict__ lamPtr) {
  int gid = blockIdx.x * 256 + threadIdx.x;   // 0..32767
  const float* p = sp + (long)gid * 32;
  float L = 0.f;
  #pragma unroll
  for (int kb = 0; kb < 32; kb++) L += p[kb];
  int half = (gid >> 11) & 1;
  so[gid] = (half ? lamPtr[0] : 1.0f) / L;
}

// ---------------- apply: O = (E1*i1 - E2*i2) @ V ----------------
// (verified round-10 version, unchanged)
__global__ __launch_bounds__(512, 2) void apply_pv(
    const u16* __restrict__ E1, const u16* __restrict__ E2,
    const u16* __restrict__ VT, const float* __restrict__ inv,
    float* __restrict__ Out)
{
  __shared__ u16 Vs[2][32768];    // 2 x [512 d][64 k] packed subtile, 128 KB
  __shared__ u16 Pb[2][4096];     // 2 x [64 q][64 k] packed subtile, 16 KB
  __shared__ float i1s[64], i2s[64];

  const int NT = 32;
  int b = blockIdx.x & 7, qt = blockIdx.x >> 3;
  int q0 = qt * 64;
  int tid = threadIdx.x;
  int wave = tid >> 6, lane = tid & 63, quad = lane >> 4, ln = lane & 15;
  int c8 = lane >> 3, ml = lane & 7;
  int r = tid >> 3, cg8 = tid & 7;            // P producer mapping: 64 rows x 8 col-groups

  const u16* e1p = E1 + ((long)b * 2048 + q0 + r) * 2048 + cg8 * 8;
  const u16* e2p = E2 + ((long)b * 2048 + q0 + r) * 2048 + cg8 * 8;
  const u16* Vbase = VT + (long)b * 2048;     // row stride 16384 (u16)
  int pw = (r >> 3) * 512 + cg8 * 64 + (r & 7) * 8;   // packed P write idx (u16)

  const f32x4 fz = {0.f, 0.f, 0.f, 0.f};
  f32x4 acc[4][4];
  #pragma unroll
  for (int i = 0; i < 4; i++)
    #pragma unroll
    for (int j = 0; j < 4; j++) acc[i][j] = fz;

  // ---- prologue ----
  if (tid < 64)       i1s[tid]       = inv[(long)(b * 2 + 0) * 2048 + q0 + tid];
  else if (tid < 128) i2s[tid - 64]  = inv[(long)(b * 2 + 1) * 2048 + q0 + (tid - 64)];
  u16x8 a1 = *(const u16x8*)(e1p);            // E(0), compiler-tracked
  u16x8 a2 = *(const u16x8*)(e2p);
  __builtin_amdgcn_sched_barrier(0);
  #pragma unroll
  for (int i = 0; i < 8; i++) {               // V(0) -> Vs[0]
    int dg = wave * 8 + i;
    glds16(Vbase + (long)(dg * 8 + ml) * 16384 + c8 * 8, &Vs[0][dg * 512]);
  }
  __builtin_amdgcn_sched_barrier(0);
  asm volatile("s_waitcnt lgkmcnt(0)" ::: "memory");   // i1s/i2s stores done
  __builtin_amdgcn_s_barrier();                        // i1s visible
  __builtin_amdgcn_sched_barrier(0);
  float i1 = i1s[r], i2 = i2s[r];
  {
    u16x8 o;
    #pragma unroll
    for (int j = 0; j < 8; j++)
      o[j] = to_bf16(b2f(a1[j]) * i1 - b2f(a2[j]) * i2);
    *(u16x8*)&Pb[0][pw] = o;                  // P(0)
  }
  a1 = *(const u16x8*)(e1p + 64);             // E(1)
  a2 = *(const u16x8*)(e2p + 64);
  __builtin_amdgcn_sched_barrier(0);
  asm volatile("s_waitcnt lgkmcnt(0)" ::: "memory");   // P(0) write done
  asm volatile("s_waitcnt vmcnt(2)" ::: "memory");     // V(0) landed, E(1) flying
  __builtin_amdgcn_sched_barrier(0);
  __builtin_amdgcn_s_barrier();
  __builtin_amdgcn_sched_barrier(0);

  // ---- main loop ----
  for (int t = 0; t < NT; t++) {
    const int p = t & 1;
    const u16* Vr = &Vs[p][0];
    const u16* Pr = &Pb[p][0];
    u16* Vw = &Vs[p ^ 1][0];
    u16* Pw = &Pb[p ^ 1][0];
    int ktv = ((t + 1 < NT) ? (t + 1) : (NT - 1)) << 6;   // V(t+1)
    int kte = ((t + 2 < NT) ? (t + 2) : (NT - 1)) << 6;   // E(t+2)
    bf16x8 vf[2][4];

    #pragma unroll
    for (int q = 0; q < 4; q++) {
      bf16x8 pf[2];
      #pragma unroll
      for (int ks = 0; ks < 2; ks++) {
        int m = q * 16 + ln;
        pf[ks] = *(const bf16x8*)&Pr[((m >> 3) * 64 + (ks * 4 + quad) * 8 + (m & 7)) * 8];
      }
      if (q == 0) {
        #pragma unroll
        for (int ks = 0; ks < 2; ks++)
          #pragma unroll
          for (int nt = 0; nt < 4; nt++) {
            int d = wave * 64 + nt * 16 + ln;
            vf[ks][nt] = *(const bf16x8*)&Vr[((d >> 3) * 64 + (ks * 4 + quad) * 8 + (d & 7)) * 8];
          }
      }
      // stage V(t+1): 2 glds16 per wave per phase
      #pragma unroll
      for (int i = 0; i < 2; i++) {
        int dg = wave * 8 + q * 2 + i;
        glds16(Vbase + (long)(dg * 8 + ml) * 16384 + ktv + c8 * 8, Vw + dg * 512);
      }
      if (q == 3) {
        __builtin_amdgcn_sched_barrier(0);
        // compiler inserts the wait for a1/a2 (E(t+1)) here; V(t+1)x8 stay out
        u16x8 o;
        #pragma unroll
        for (int j = 0; j < 8; j++)
          o[j] = to_bf16(b2f(a1[j]) * i1 - b2f(a2[j]) * i2);
        *(u16x8*)&Pw[pw] = o;                             // P(t+1)
        a1 = *(const u16x8*)(e1p + kte);                  // E(t+2)
        a2 = *(const u16x8*)(e2p + kte);
      }
      __builtin_amdgcn_sched_barrier(0);
      __builtin_amdgcn_s_barrier();
      asm volatile("s_waitcnt lgkmcnt(0)" ::: "memory");
      __builtin_amdgcn_sched_barrier(0);
      __builtin_amdgcn_s_setprio(1);
      #pragma unroll
      for (int ks = 0; ks < 2; ks++)
        #pragma unroll
        for (int nt = 0; nt < 4; nt++)
          acc[q][nt] = __builtin_amdgcn_mfma_f32_16x16x32_bf16(pf[ks], vf[ks][nt], acc[q][nt], 0, 0, 0);
      __builtin_amdgcn_s_setprio(0);
      __builtin_amdgcn_sched_barrier(0);
      if (q == 3) asm volatile("s_waitcnt vmcnt(2)" ::: "memory");  // V(t+1) landed
      __builtin_amdgcn_s_barrier();
      __builtin_amdgcn_sched_barrier(0);
    }
  }

  #pragma unroll
  for (int mt = 0; mt < 4; mt++)
    #pragma unroll
    for (int nt = 0; nt < 4; nt++)
      #pragma unroll
      for (int r2 = 0; r2 < 4; r2++)
        Out[((long)b * 2048 + q0 + mt * 16 + quad * 4 + r2) * 512 + wave * 64 + nt * 16 + ln] =
            acc[mt][nt][r2];
}

// ---------------- launch ----------------

extern "C" void kernel_launch(void* const* d_in, const int* in_sizes, int n_in,
                              void* d_out, int out_size, void* d_ws, size_t ws_size,
                              hipStream_t stream)
{
  const float* X   = (const float*)d_in[0];
  const float* lam = (const float*)d_in[1];
  const float* Wq  = (const float*)d_in[2];
  const float* bq  = (const float*)d_in[3];
  const float* Wk  = (const float*)d_in[4];
  const float* bk  = (const float*)d_in[5];
  const float* Wv  = (const float*)d_in[6];
  const float* bv  = (const float*)d_in[7];
  float* Out = (float*)d_out;
  char* ws = (char*)d_ws;

  u16*  WqkT   = (u16*)(ws + 0);           //  4 MB [2048][1024]
  u16*  WvT    = (u16*)(ws + 4194304);     //  1 MB [512][1024]
  float* bqk   = (float*)(ws + 5242880);   //  8 KB [2048]
  u16*  Qb     = (u16*)(ws + 6291456);     // 32 MB [16384][1024]
  u16*  Kb     = (u16*)(ws + 39845888);    // 32 MB [16384][1024]
  u16*  VTb    = (u16*)(ws + 73400320);    // 16 MB [512][16384]
  u16*  Xb     = (u16*)(ws + 90177536);    // 32 MB [16384][1024]
  u16*  E1     = (u16*)(ws + 90177536);    // 64 MB, overlaps Xb (Xb dead first)
  u16*  E2     = (u16*)(ws + 157286400);   // 64 MB
  float* statsP= (float*)(ws + 224395264); //  4 MB [8][2][2048][32]
  float* invD  = (float*)(ws + 228589568); // 128 KB [8][2][2048]

  cvt_x<<<16384, 256, 0, stream>>>((const float4*)X, (u16x4*)Xb, 4194304);
  transpose_cvt<<<dim3(16, 16), dim3(64, 4), 0, stream>>>(Wq, WqkT, 1024, 1024);
  transpose_cvt<<<dim3(16, 16), dim3(64, 4), 0, stream>>>(Wk, WqkT + 1024 * 1024, 1024, 1024);
  transpose_cvt<<<dim3(8, 16),  dim3(64, 4), 0, stream>>>(Wv, WvT, 1024, 512);
  concat2<<<8, 256, 0, stream>>>(bq, bk, bqk, 1024);

  // [Q|K] = Xb @ WqkT^T + bqk, persistent 256^2 tiles (2 tm-subs per block)
  gemm_nt256p<<<dim3(8, 32), 512, 0, stream>>>(Xb, WqkT, Qb, Kb, 1024, 1024,
                                               1.0f, bqk, 1);
  // V^T[d][m] = sum_e WvT[d][e]*Xb[m][e] + bv[d]  (legacy 128^2 kernel)
  gemm_nt<<<dim3(128, 4), 256, 0, stream>>>(WvT, 1024, Xb, 1024,
                                            VTb, VTb, 1 << 30, 16384,
                                            1024, 1.0f, bv, 2);

  const float s = 0.044194173824159216f;  // 1/sqrt(512)
  gemm_s256p<<<dim3(8, 2, 16), 512, 0, stream>>>(Qb, Kb, E1, E2, statsP, s);

  stats_reduce<<<128, 256, 0, stream>>>(statsP, invD, lam);
  apply_pv<<<256, 512, 0, stream>>>(E1, E2, VTb, invD, Out);
}

// Round 7
// 461.050 us; speedup vs baseline: 1.0388x; 1.0301x over previous
//
#include <hip/hip_runtime.h>

// DiffAttn on MI355X, round 14.
// Round-13 post-mortem: period/T halves when chunk halves (10560 cyc @BK64 vs
// 4950 @BK32) while MFMA+LDS floors are ~1100 cyc -> the pipeline is
// serialized on HBM latency+service with prefetch depth 1 (every schedule so
// far waited on a load issued one body earlier). Fix: depth-2 windows for
// BOTH operands: A and B triple-buffered at BK=32 (3x16K + 3x16K = 96 KB,
// + 64 KB epilogue buffer = exactly 160 KB LDS, the gfx950 per-WG max).
// Stage (T+2) at tile T; vmcnt(4) at tile end lands the (T+1) pair issued a
// full tile earlier (2-period landing window). Ledger: prologue A0,B0,A1,B1
// -> vmcnt(4); steady 8 outstanding -> vmcnt(4); clamped tails re-stage
// identical bytes into retired buffers (benign); vmcnt(0) before endpgm.
// apply_pv / legacy V-GEMM / conversions unchanged (verified).

typedef unsigned short u16;
typedef short    bf16x8 __attribute__((ext_vector_type(8)));
typedef unsigned short u16x8 __attribute__((ext_vector_type(8)));
typedef unsigned short u16x4 __attribute__((ext_vector_type(4)));
typedef float    f32x4  __attribute__((ext_vector_type(4)));

typedef __attribute__((address_space(3))) unsigned int       lds_uint;
typedef __attribute__((address_space(1))) const unsigned int gl_uint;

__device__ __forceinline__ void glds16(const void* g, void* l) {
  __builtin_amdgcn_global_load_lds((gl_uint*)g, (lds_uint*)l, 16, 0, 0);
}

__device__ __forceinline__ u16 to_bf16(float f) {
  unsigned u = __float_as_uint(f);
  return (u16)((u + 0x7FFFu + ((u >> 16) & 1u)) >> 16);  // RNE
}
__device__ __forceinline__ float b2f(u16 h) {
  return __uint_as_float(((unsigned)h) << 16);
}

// ---------------- conversion kernels ----------------

__global__ void cvt_x(const float4* __restrict__ in, u16x4* __restrict__ out, int n4) {
  int i = blockIdx.x * 256 + threadIdx.x;
  if (i >= n4) return;
  float4 v = in[i];
  u16x4 o;
  o[0] = to_bf16(v.x); o[1] = to_bf16(v.y); o[2] = to_bf16(v.z); o[3] = to_bf16(v.w);
  out[i] = o;
}

__global__ void transpose_cvt(const float* __restrict__ in, u16* __restrict__ out,
                              int R, int C) {
  __shared__ float t[64][65];
  int c0 = blockIdx.x * 64, r0 = blockIdx.y * 64;
  int tx = threadIdx.x, ty = threadIdx.y;
  #pragma unroll
  for (int i = 0; i < 64; i += 4)
    t[ty + i][tx] = in[(long)(r0 + ty + i) * C + c0 + tx];
  __syncthreads();
  #pragma unroll
  for (int i = 0; i < 64; i += 4)
    out[(long)(c0 + ty + i) * R + r0 + tx] = to_bf16(t[tx][ty + i]);
}

__global__ void concat2(const float* __restrict__ a, const float* __restrict__ b,
                        float* __restrict__ o, int n) {
  int i = blockIdx.x * 256 + threadIdx.x;
  if (i < n) o[i] = a[i];
  else if (i < 2 * n) o[i] = b[i - n];
}

// GROUP_M=4 swizzle (legacy gemm_nt only).
__device__ __forceinline__ void swizzle_tiles(int& tm, int& tn) {
  int nx = gridDim.x;
  int lin = blockIdx.y * nx + blockIdx.x;
  int span = nx * 4;
  int group = lin / span;
  int ing = lin % span;
  tm = group * 4 + (ing & 3);
  tn = ing >> 2;
}

// ---------------- legacy 128x128 NT GEMM (kept for the V projection) --------
__global__ __launch_bounds__(256, 4) void gemm_nt(
    const u16* __restrict__ A, int lda,
    const u16* __restrict__ B, int ldb,
    u16* __restrict__ C1, u16* __restrict__ C2, int splitN, int ldc,
    int Kd, float scale,
    const float* __restrict__ bias, int biasMode)   // 0 none, 1 per-col, 2 per-row
{
  __shared__ u16 SM[2][8192];
  u16* As = SM[0];
  u16* Bs = SM[1];

  int tid = threadIdx.x;
  int wave = tid >> 6, lane = tid & 63;
  int quad = lane >> 4, ln = lane & 15;
  int wm = wave >> 1, wn = wave & 1;
  int tm, tn;
  swizzle_tiles(tm, tn);
  int c8 = lane >> 3, ml = lane & 7;

  const f32x4 fz = {0.f, 0.f, 0.f, 0.f};
  f32x4 acc[4][4];
  #pragma unroll
  for (int i = 0; i < 4; i++)
    #pragma unroll
    for (int j = 0; j < 4; j++) acc[i][j] = fz;

  const u16* Abase = A + (long)(tm * 128 + ml) * lda + c8 * 8;
  const u16* Bbase = B + (long)(tn * 128 + ml) * ldb + c8 * 8;

  for (int kt = 0; kt < Kd; kt += 64) {
    __syncthreads();
    #pragma unroll
    for (int i = 0; i < 4; i++) {
      int mg = wave * 4 + i;
      glds16(Abase + (long)mg * 8 * lda + kt, &As[mg * 512]);
      glds16(Bbase + (long)mg * 8 * ldb + kt, &Bs[mg * 512]);
    }
    __syncthreads();
    #pragma unroll
    for (int ks = 0; ks < 2; ks++) {
      bf16x8 af[4], bfr[4];
      int c = ks * 4 + quad;
      #pragma unroll
      for (int mt = 0; mt < 4; mt++) {
        int m = wm * 64 + mt * 16 + ln;
        af[mt] = *(const bf16x8*)&As[((m >> 3) * 64 + c * 8 + (m & 7)) * 8];
      }
      #pragma unroll
      for (int nt = 0; nt < 4; nt++) {
        int n = wn * 64 + nt * 16 + ln;
        bfr[nt] = *(const bf16x8*)&Bs[((n >> 3) * 64 + c * 8 + (n & 7)) * 8];
      }
      #pragma unroll
      for (int mt = 0; mt < 4; mt++)
        #pragma unroll
        for (int nt = 0; nt < 4; nt++)
          acc[mt][nt] = __builtin_amdgcn_mfma_f32_16x16x32_bf16(af[mt], bfr[nt], acc[mt][nt], 0, 0, 0);
    }
  }

  int rowBase = tm * 128 + wm * 64;
  int colBase = tn * 128 + wn * 64;
  u16* Cw = C1; int outCol = colBase;
  if (colBase >= splitN) { Cw = C2; outCol = colBase - splitN; }
  u16* eb = &SM[0][0] + wave * 4096;

  __syncthreads();
  #pragma unroll
  for (int mt = 0; mt < 4; mt++) {
    #pragma unroll
    for (int nt = 0; nt < 4; nt++) {
      int colL = nt * 16 + ln;
      float bcol = (biasMode == 1) ? bias[colBase + colL] : 0.f;
      #pragma unroll
      for (int r = 0; r < 4; r++) {
        int rowL = mt * 16 + quad * 4 + r;
        float brow = (biasMode == 2) ? bias[rowBase + rowL] : 0.f;
        float v = acc[mt][nt][r] * scale + bcol + brow;
        eb[rowL * 64 + (((colL >> 3) ^ (rowL & 7)) << 3) + (colL & 7)] = to_bf16(v);
      }
    }
  }
  {
    int row = lane;
    long gr = (long)(rowBase + row) * ldc + outCol;
    #pragma unroll
    for (int c = 0; c < 8; c++) {
      u16x8 ch = *(const u16x8*)&eb[row * 64 + ((c ^ (row & 7)) << 3)];
      *(u16x8*)&Cw[gr + c * 8] = ch;
    }
  }
}

// ======================= persistent 256-wide GEMM kernels =====================
// 256x256 output tiles, 8 waves (2m x 4n), per-wave 128x64 acc[8][4]. BK=32.
// LDS (u16 idx): A tbuf @0 + (T%3)*8192, B tbuf @24576 + (T%3)*8192,
// epilogue eb @49152 + wave*4096 (64x64). Total 81920 u16 = 160 KB (gfx950
// per-WG max; AITER attn uses the same).
// Staging lane map: dr=((lane>>5)<<3)+(lane&7), cg=(lane>>3)&3; packed layout
// elem(row,col) -> (row>>3)*256 + (col>>3)*64 + (row&7)*8 + (col&7) [u16]
// == lane-linear glds16 dest. Fragment read (row m, quad): b128 @
// ((m>>3)*32 + quad*8 + (m&7))*8.
// Pipeline depth 2: at tile T stage A(T+2),B(T+2); vmcnt(4) at tile end lands
// the (T+1) pair (issued one full tile earlier).

// ---------------- persistent S GEMM: E=exp(S) + per-64col sum partials -------
__global__ __launch_bounds__(512, 2) void gemm_s256p(
    const u16* __restrict__ Q, const u16* __restrict__ K,
    u16* __restrict__ E1, u16* __restrict__ E2,
    float* __restrict__ statsP, float scale)
{
  __shared__ u16 SM[81920];   // 160 KB

  int bz = blockIdx.z >> 1, half = blockIdx.z & 1;
  const u16* A = Q + (long)bz * 2097152 + half * 512;
  const u16* B = K + (long)bz * 2097152 + half * 512;
  u16* Ed = (half ? E2 : E1) + (long)bz * 4194304;
  float* sp = statsP + (long)blockIdx.z * 65536;

  int tn = blockIdx.x;       // 0..7
  int tmg = blockIdx.y;      // 0..1
  int tid = threadIdx.x;
  int wave = tid >> 6, lane = tid & 63, quad = lane >> 4, ln = lane & 15;
  int wm = wave >> 2, wn = wave & 3;
  int dr = ((lane >> 5) << 3) + (lane & 7);
  int cg = (lane >> 3) & 3;
  (void)dr; (void)cg;   // folded into Abase/Bbase

  const f32x4 fz = {0.f, 0.f, 0.f, 0.f};
  f32x4 acc[8][4];
  #pragma unroll
  for (int i = 0; i < 8; i++)
    #pragma unroll
    for (int j = 0; j < 4; j++) acc[i][j] = fz;

  const u16* Abase = A + (long)(tmg * 1024 + wave * 32 + ((lane >> 5) << 3) + (lane & 7)) * 1024 + ((lane >> 3) & 3) * 8;
  const u16* Bbase = B + (long)(tn * 256 + wave * 32 + ((lane >> 5) << 3) + (lane & 7)) * 1024 + ((lane >> 3) & 3) * 8;
  u16* ldsA0 = SM;               // + (T%3)*8192, per-wave dst +wave*1024
  u16* ldsB0 = SM + 24576;       // + (T%3)*8192
  u16* eb = SM + 49152 + wave * 4096;

  // ---- prologue: A(0),B(0),A(1),B(1); wait A(0)+B(0); (1)-pair in flight ----
  glds16(Abase,                  ldsA0 + wave * 1024);
  glds16(Abase + 16 * 1024,      ldsA0 + wave * 1024 + 512);
  glds16(Bbase,                  ldsB0 + wave * 1024);
  glds16(Bbase + 16 * 1024,      ldsB0 + wave * 1024 + 512);
  glds16(Abase + 32,             ldsA0 + 8192 + wave * 1024);
  glds16(Abase + 16 * 1024 + 32, ldsA0 + 8192 + wave * 1024 + 512);
  glds16(Bbase + 32,             ldsB0 + 8192 + wave * 1024);
  glds16(Bbase + 16 * 1024 + 32, ldsB0 + 8192 + wave * 1024 + 512);
  asm volatile("s_waitcnt vmcnt(4)" ::: "memory");
  __builtin_amdgcn_s_barrier();
  __builtin_amdgcn_sched_barrier(0);

  for (int T = 0; T < 64; T++) {
    const u16* Ar = ldsA0 + (T % 3) * 8192;
    const u16* Br = ldsB0 + (T % 3) * 8192;

    // ---- stage A(T+2), B(T+2) (clamped tail re-stages identical bytes) ----
    {
      int Ta = (T + 2 < 64) ? T + 2 : 63;
      long roff = (long)((Ta >> 4) * 256) * 1024 + ((Ta & 15) << 5);
      u16* dA = ldsA0 + (Ta % 3) * 8192 + wave * 1024;
      glds16(Abase + roff,             dA);
      glds16(Abase + roff + 16 * 1024, dA + 512);
      int ktB = (Ta & 15) << 5;
      u16* dB = ldsB0 + (Ta % 3) * 8192 + wave * 1024;
      glds16(Bbase + ktB,             dB);
      glds16(Bbase + ktB + 16 * 1024, dB + 512);
    }
    __builtin_amdgcn_sched_barrier(0);

    // ---- fragments + 32 MFMA (compiler-scheduled lgkm interleave) ----
    bf16x8 bfr[4];
    #pragma unroll
    for (int nt = 0; nt < 4; nt++) {
      int n = wn * 64 + nt * 16 + ln;
      bfr[nt] = *(const bf16x8*)(Br + ((n >> 3) * 32 + quad * 8 + (n & 7)) * 8);
    }
    #pragma unroll
    for (int g = 0; g < 8; g++) {
      int m = wm * 128 + g * 16 + ln;
      bf16x8 af = *(const bf16x8*)(Ar + ((m >> 3) * 32 + quad * 8 + (m & 7)) * 8);
      #pragma unroll
      for (int nt = 0; nt < 4; nt++)
        acc[g][nt] = __builtin_amdgcn_mfma_f32_16x16x32_bf16(af, bfr[nt], acc[g][nt], 0, 0, 0);
    }

    asm volatile("s_waitcnt vmcnt(4)" ::: "memory");  // (T+1) pair landed
    __builtin_amdgcn_s_barrier();
    __builtin_amdgcn_sched_barrier(0);

    // ---- in-pipeline epilogue at each sub boundary (wave-private eb) ----
    if ((T & 15) == 15) {
      int sub = T >> 4;
      int rowBaseW = (tmg * 4 + sub) * 256 + wm * 128;
      int colBase = tn * 256 + wn * 64;
      int kb = tn * 4 + wn;
      #pragma unroll
      for (int h = 0; h < 2; h++) {
        #pragma unroll
        for (int mt = 0; mt < 4; mt++) {
          #pragma unroll
          for (int nt = 0; nt < 4; nt++) {
            int colL = nt * 16 + ln;
            #pragma unroll
            for (int r = 0; r < 4; r++) {
              int rowL = mt * 16 + quad * 4 + r;
              eb[rowL * 64 + (((colL >> 3) ^ (rowL & 7)) << 3) + (colL & 7)] =
                  to_bf16(__expf(acc[h * 4 + mt][nt][r] * scale));
            }
          }
        }
        {
          int row = lane;
          u16x8 ch[8];
          #pragma unroll
          for (int c = 0; c < 8; c++)
            ch[c] = *(const u16x8*)&eb[row * 64 + ((c ^ (row & 7)) << 3)];
          u16* Ep = Ed + (long)(rowBaseW + h * 64 + row) * 2048 + colBase;
          #pragma unroll
          for (int c = 0; c < 8; c++)
            *(u16x8*)&Ep[c * 8] = ch[c];
          float L = 0.f;
          #pragma unroll
          for (int c = 0; c < 8; c++)
            #pragma unroll
            for (int j = 0; j < 8; j++) L += b2f(ch[c][j]);
          sp[(rowBaseW + h * 64 + row) * 32 + kb] = L;
        }
      }
      #pragma unroll
      for (int i = 0; i < 8; i++)
        #pragma unroll
        for (int j = 0; j < 4; j++) acc[i][j] = fz;
    }
  }
  asm volatile("s_waitcnt vmcnt(0)" ::: "memory");
}

// ---------------- persistent NT GEMM for the QK projection -------------------
__global__ __launch_bounds__(512, 2) void gemm_nt256p(
    const u16* __restrict__ A, const u16* __restrict__ B,
    u16* __restrict__ C1, u16* __restrict__ C2, int splitN, int ldc,
    float scale, const float* __restrict__ bias, int biasMode)
{
  __shared__ u16 SM[81920];   // 160 KB

  int tn = blockIdx.x;       // 0..7
  int tmg = blockIdx.y;      // 0..31
  int tid = threadIdx.x;
  int wave = tid >> 6, lane = tid & 63, quad = lane >> 4, ln = lane & 15;
  int wm = wave >> 2, wn = wave & 3;

  const f32x4 fz = {0.f, 0.f, 0.f, 0.f};
  f32x4 acc[8][4];
  #pragma unroll
  for (int i = 0; i < 8; i++)
    #pragma unroll
    for (int j = 0; j < 4; j++) acc[i][j] = fz;

  const u16* Abase = A + (long)(tmg * 512 + wave * 32 + ((lane >> 5) << 3) + (lane & 7)) * 1024 + ((lane >> 3) & 3) * 8;
  const u16* Bbase = B + (long)(tn * 256 + wave * 32 + ((lane >> 5) << 3) + (lane & 7)) * 1024 + ((lane >> 3) & 3) * 8;
  u16* ldsA0 = SM;
  u16* ldsB0 = SM + 24576;
  u16* eb = SM + 49152 + wave * 4096;

  glds16(Abase,                  ldsA0 + wave * 1024);
  glds16(Abase + 16 * 1024,      ldsA0 + wave * 1024 + 512);
  glds16(Bbase,                  ldsB0 + wave * 1024);
  glds16(Bbase + 16 * 1024,      ldsB0 + wave * 1024 + 512);
  glds16(Abase + 32,             ldsA0 + 8192 + wave * 1024);
  glds16(Abase + 16 * 1024 + 32, ldsA0 + 8192 + wave * 1024 + 512);
  glds16(Bbase + 32,             ldsB0 + 8192 + wave * 1024);
  glds16(Bbase + 16 * 1024 + 32, ldsB0 + 8192 + wave * 1024 + 512);
  asm volatile("s_waitcnt vmcnt(4)" ::: "memory");
  __builtin_amdgcn_s_barrier();
  __builtin_amdgcn_sched_barrier(0);

  for (int T = 0; T < 64; T++) {
    const u16* Ar = ldsA0 + (T % 3) * 8192;
    const u16* Br = ldsB0 + (T % 3) * 8192;

    {
      int Ta = (T + 2 < 64) ? T + 2 : 63;
      long roff = (long)((Ta >> 5) * 256) * 1024 + ((Ta & 31) << 5);
      u16* dA = ldsA0 + (Ta % 3) * 8192 + wave * 1024;
      glds16(Abase + roff,             dA);
      glds16(Abase + roff + 16 * 1024, dA + 512);
      int ktB = (Ta & 31) << 5;
      u16* dB = ldsB0 + (Ta % 3) * 8192 + wave * 1024;
      glds16(Bbase + ktB,             dB);
      glds16(Bbase + ktB + 16 * 1024, dB + 512);
    }
    __builtin_amdgcn_sched_barrier(0);

    bf16x8 bfr[4];
    #pragma unroll
    for (int nt = 0; nt < 4; nt++) {
      int n = wn * 64 + nt * 16 + ln;
      bfr[nt] = *(const bf16x8*)(Br + ((n >> 3) * 32 + quad * 8 + (n & 7)) * 8);
    }
    #pragma unroll
    for (int g = 0; g < 8; g++) {
      int m = wm * 128 + g * 16 + ln;
      bf16x8 af = *(const bf16x8*)(Ar + ((m >> 3) * 32 + quad * 8 + (m & 7)) * 8);
      #pragma unroll
      for (int nt = 0; nt < 4; nt++)
        acc[g][nt] = __builtin_amdgcn_mfma_f32_16x16x32_bf16(af, bfr[nt], acc[g][nt], 0, 0, 0);
    }

    asm volatile("s_waitcnt vmcnt(4)" ::: "memory");
    __builtin_amdgcn_s_barrier();
    __builtin_amdgcn_sched_barrier(0);

    if ((T & 31) == 31) {
      int sub = T >> 5;
      int rowBaseW = (tmg * 2 + sub) * 256 + wm * 128;
      int colBase = tn * 256 + wn * 64;
      u16* Cw = C1; int outCol = colBase;
      if (colBase >= splitN) { Cw = C2; outCol = colBase - splitN; }
      #pragma unroll
      for (int h = 0; h < 2; h++) {
        #pragma unroll
        for (int mt = 0; mt < 4; mt++) {
          #pragma unroll
          for (int nt = 0; nt < 4; nt++) {
            int colL = nt * 16 + ln;
            float bcol = (biasMode == 1) ? bias[colBase + colL] : 0.f;
            #pragma unroll
            for (int r = 0; r < 4; r++) {
              int rowL = mt * 16 + quad * 4 + r;
              float brow = (biasMode == 2) ? bias[rowBaseW + h * 64 + rowL] : 0.f;
              float v = acc[h * 4 + mt][nt][r] * scale + bcol + brow;
              eb[rowL * 64 + (((colL >> 3) ^ (rowL & 7)) << 3) + (colL & 7)] = to_bf16(v);
            }
          }
        }
        {
          int row = lane;
          long gr = (long)(rowBaseW + h * 64 + row) * ldc + outCol;
          #pragma unroll
          for (int c = 0; c < 8; c++) {
            u16x8 ch = *(const u16x8*)&eb[row * 64 + ((c ^ (row & 7)) << 3)];
            *(u16x8*)&Cw[gr + c * 8] = ch;
          }
        }
      }
      #pragma unroll
      for (int i = 0; i < 8; i++)
        #pragma unroll
        for (int j = 0; j < 4; j++) acc[i][j] = fz;
    }
  }
  asm volatile("s_waitcnt vmcnt(0)" ::: "memory");
}

// ---------------- stats reduce: 32 partials -> inv-denominator ----------------
__global__ void stats_reduce(const float* __restrict__ sp, float* __restrict__ so,
                             const float* __restrict__ lamPtr) {
  int gid = blockIdx.x * 256 + threadIdx.x;   // 0..32767
  const float* p = sp + (long)gid * 32;
  float L = 0.f;
  #pragma unroll
  for (int kb = 0; kb < 32; kb++) L += p[kb];
  int half = (gid >> 11) & 1;
  so[gid] = (half ? lamPtr[0] : 1.0f) / L;
}

// ---------------- apply: O = (E1*i1 - E2*i2) @ V ----------------
// (verified round-10 version, unchanged)
__global__ __launch_bounds__(512, 2) void apply_pv(
    const u16* __restrict__ E1, const u16* __restrict__ E2,
    const u16* __restrict__ VT, const float* __restrict__ inv,
    float* __restrict__ Out)
{
  __shared__ u16 Vs[2][32768];    // 2 x [512 d][64 k] packed subtile, 128 KB
  __shared__ u16 Pb[2][4096];     // 2 x [64 q][64 k] packed subtile, 16 KB
  __shared__ float i1s[64], i2s[64];

  const int NT = 32;
  int b = blockIdx.x & 7, qt = blockIdx.x >> 3;
  int q0 = qt * 64;
  int tid = threadIdx.x;
  int wave = tid >> 6, lane = tid & 63, quad = lane >> 4, ln = lane & 15;
  int c8 = lane >> 3, ml = lane & 7;
  int r = tid >> 3, cg8 = tid & 7;            // P producer mapping: 64 rows x 8 col-groups

  const u16* e1p = E1 + ((long)b * 2048 + q0 + r) * 2048 + cg8 * 8;
  const u16* e2p = E2 + ((long)b * 2048 + q0 + r) * 2048 + cg8 * 8;
  const u16* Vbase = VT + (long)b * 2048;     // row stride 16384 (u16)
  int pw = (r >> 3) * 512 + cg8 * 64 + (r & 7) * 8;   // packed P write idx (u16)

  const f32x4 fz = {0.f, 0.f, 0.f, 0.f};
  f32x4 acc[4][4];
  #pragma unroll
  for (int i = 0; i < 4; i++)
    #pragma unroll
    for (int j = 0; j < 4; j++) acc[i][j] = fz;

  // ---- prologue ----
  if (tid < 64)       i1s[tid]       = inv[(long)(b * 2 + 0) * 2048 + q0 + tid];
  else if (tid < 128) i2s[tid - 64]  = inv[(long)(b * 2 + 1) * 2048 + q0 + (tid - 64)];
  u16x8 a1 = *(const u16x8*)(e1p);            // E(0), compiler-tracked
  u16x8 a2 = *(const u16x8*)(e2p);
  __builtin_amdgcn_sched_barrier(0);
  #pragma unroll
  for (int i = 0; i < 8; i++) {               // V(0) -> Vs[0]
    int dg = wave * 8 + i;
    glds16(Vbase + (long)(dg * 8 + ml) * 16384 + c8 * 8, &Vs[0][dg * 512]);
  }
  __builtin_amdgcn_sched_barrier(0);
  asm volatile("s_waitcnt lgkmcnt(0)" ::: "memory");   // i1s/i2s stores done
  __builtin_amdgcn_s_barrier();                        // i1s visible
  __builtin_amdgcn_sched_barrier(0);
  float i1 = i1s[r], i2 = i2s[r];
  {
    u16x8 o;
    #pragma unroll
    for (int j = 0; j < 8; j++)
      o[j] = to_bf16(b2f(a1[j]) * i1 - b2f(a2[j]) * i2);
    *(u16x8*)&Pb[0][pw] = o;                  // P(0)
  }
  a1 = *(const u16x8*)(e1p + 64);             // E(1)
  a2 = *(const u16x8*)(e2p + 64);
  __builtin_amdgcn_sched_barrier(0);
  asm volatile("s_waitcnt lgkmcnt(0)" ::: "memory");   // P(0) write done
  asm volatile("s_waitcnt vmcnt(2)" ::: "memory");     // V(0) landed, E(1) flying
  __builtin_amdgcn_sched_barrier(0);
  __builtin_amdgcn_s_barrier();
  __builtin_amdgcn_sched_barrier(0);

  // ---- main loop ----
  for (int t = 0; t < NT; t++) {
    const int p = t & 1;
    const u16* Vr = &Vs[p][0];
    const u16* Pr = &Pb[p][0];
    u16* Vw = &Vs[p ^ 1][0];
    u16* Pw = &Pb[p ^ 1][0];
    int ktv = ((t + 1 < NT) ? (t + 1) : (NT - 1)) << 6;   // V(t+1)
    int kte = ((t + 2 < NT) ? (t + 2) : (NT - 1)) << 6;   // E(t+2)
    bf16x8 vf[2][4];

    #pragma unroll
    for (int q = 0; q < 4; q++) {
      bf16x8 pf[2];
      #pragma unroll
      for (int ks = 0; ks < 2; ks++) {
        int m = q * 16 + ln;
        pf[ks] = *(const bf16x8*)&Pr[((m >> 3) * 64 + (ks * 4 + quad) * 8 + (m & 7)) * 8];
      }
      if (q == 0) {
        #pragma unroll
        for (int ks = 0; ks < 2; ks++)
          #pragma unroll
          for (int nt = 0; nt < 4; nt++) {
            int d = wave * 64 + nt * 16 + ln;
            vf[ks][nt] = *(const bf16x8*)&Vr[((d >> 3) * 64 + (ks * 4 + quad) * 8 + (d & 7)) * 8];
          }
      }
      // stage V(t+1): 2 glds16 per wave per phase
      #pragma unroll
      for (int i = 0; i < 2; i++) {
        int dg = wave * 8 + q * 2 + i;
        glds16(Vbase + (long)(dg * 8 + ml) * 16384 + ktv + c8 * 8, Vw + dg * 512);
      }
      if (q == 3) {
        __builtin_amdgcn_sched_barrier(0);
        // compiler inserts the wait for a1/a2 (E(t+1)) here; V(t+1)x8 stay out
        u16x8 o;
        #pragma unroll
        for (int j = 0; j < 8; j++)
          o[j] = to_bf16(b2f(a1[j]) * i1 - b2f(a2[j]) * i2);
        *(u16x8*)&Pw[pw] = o;                             // P(t+1)
        a1 = *(const u16x8*)(e1p + kte);                  // E(t+2)
        a2 = *(const u16x8*)(e2p + kte);
      }
      __builtin_amdgcn_sched_barrier(0);
      __builtin_amdgcn_s_barrier();
      asm volatile("s_waitcnt lgkmcnt(0)" ::: "memory");
      __builtin_amdgcn_sched_barrier(0);
      __builtin_amdgcn_s_setprio(1);
      #pragma unroll
      for (int ks = 0; ks < 2; ks++)
        #pragma unroll
        for (int nt = 0; nt < 4; nt++)
          acc[q][nt] = __builtin_amdgcn_mfma_f32_16x16x32_bf16(pf[ks], vf[ks][nt], acc[q][nt], 0, 0, 0);
      __builtin_amdgcn_s_setprio(0);
      __builtin_amdgcn_sched_barrier(0);
      if (q == 3) asm volatile("s_waitcnt vmcnt(2)" ::: "memory");  // V(t+1) landed
      __builtin_amdgcn_s_barrier();
      __builtin_amdgcn_sched_barrier(0);
    }
  }

  #pragma unroll
  for (int mt = 0; mt < 4; mt++)
    #pragma unroll
    for (int nt = 0; nt < 4; nt++)
      #pragma unroll
      for (int r2 = 0; r2 < 4; r2++)
        Out[((long)b * 2048 + q0 + mt * 16 + quad * 4 + r2) * 512 + wave * 64 + nt * 16 + ln] =
            acc[mt][nt][r2];
}

// ---------------- launch ----------------

extern "C" void kernel_launch(void* const* d_in, const int* in_sizes, int n_in,
                              void* d_out, int out_size, void* d_ws, size_t ws_size,
                              hipStream_t stream)
{
  const float* X   = (const float*)d_in[0];
  const float* lam = (const float*)d_in[1];
  const float* Wq  = (const float*)d_in[2];
  const float* bq  = (const float*)d_in[3];
  const float* Wk  = (const float*)d_in[4];
  const float* bk  = (const float*)d_in[5];
  const float* Wv  = (const float*)d_in[6];
  const float* bv  = (const float*)d_in[7];
  float* Out = (float*)d_out;
  char* ws = (char*)d_ws;

  u16*  WqkT   = (u16*)(ws + 0);           //  4 MB [2048][1024]
  u16*  WvT    = (u16*)(ws + 4194304);     //  1 MB [512][1024]
  float* bqk   = (float*)(ws + 5242880);   //  8 KB [2048]
  u16*  Qb     = (u16*)(ws + 6291456);     // 32 MB [16384][1024]
  u16*  Kb     = (u16*)(ws + 39845888);    // 32 MB [16384][1024]
  u16*  VTb    = (u16*)(ws + 73400320);    // 16 MB [512][16384]
  u16*  Xb     = (u16*)(ws + 90177536);    // 32 MB [16384][1024]
  u16*  E1     = (u16*)(ws + 90177536);    // 64 MB, overlaps Xb (Xb dead first)
  u16*  E2     = (u16*)(ws + 157286400);   // 64 MB
  float* statsP= (float*)(ws + 224395264); //  4 MB [8][2][2048][32]
  float* invD  = (float*)(ws + 228589568); // 128 KB [8][2][2048]

  cvt_x<<<16384, 256, 0, stream>>>((const float4*)X, (u16x4*)Xb, 4194304);
  transpose_cvt<<<dim3(16, 16), dim3(64, 4), 0, stream>>>(Wq, WqkT, 1024, 1024);
  transpose_cvt<<<dim3(16, 16), dim3(64, 4), 0, stream>>>(Wk, WqkT + 1024 * 1024, 1024, 1024);
  transpose_cvt<<<dim3(8, 16),  dim3(64, 4), 0, stream>>>(Wv, WvT, 1024, 512);
  concat2<<<8, 256, 0, stream>>>(bq, bk, bqk, 1024);

  // [Q|K] = Xb @ WqkT^T + bqk, persistent 256^2 tiles (2 tm-subs per block)
  gemm_nt256p<<<dim3(8, 32), 512, 0, stream>>>(Xb, WqkT, Qb, Kb, 1024, 1024,
                                               1.0f, bqk, 1);
  // V^T[d][m] = sum_e WvT[d][e]*Xb[m][e] + bv[d]  (legacy 128^2 kernel)
  gemm_nt<<<dim3(128, 4), 256, 0, stream>>>(WvT, 1024, Xb, 1024,
                                            VTb, VTb, 1 << 30, 16384,
                                            1024, 1.0f, bv, 2);

  const float s = 0.044194173824159216f;  // 1/sqrt(512)
  gemm_s256p<<<dim3(8, 2, 16), 512, 0, stream>>>(Qb, Kb, E1, E2, statsP, s);

  stats_reduce<<<128, 256, 0, stream>>>(statsP, invD, lam);
  apply_pv<<<256, 512, 0, stream>>>(E1, E2, VTb, invD, Out);
}

// Round 8
// 460.952 us; speedup vs baseline: 1.0390x; 1.0002x over previous
//
#include <hip/hip_runtime.h>

// DiffAttn on MI355X, round 15.
// Synthesis of rounds 8-14 vs learn_hip m196/m201/m218: fine phase interleave
// was only ever tested at shallow K (8 tiles/block, overhead-dominated) and
// deep K was only tested coarse. This round: round-8's verified 4-phase BK=64
// core (16-MFMA clusters, setprio, counted vmcnt(4)/tile) made PERSISTENT:
// 32 continuous K-tiles/block (4 output subtiles for gemm_s, 2 for the QK
// projection), in-pipeline epilogue in a disjoint eb (4 KB/wave, 4x32-row
// chunks, shfl_xor(32) merges the split row-sum). LDS = A dbuf 64K + B dbuf
// 64K + eb 32K = 160 KB. Ledger per tile T: q0/q1 stage A(T+1)->buf[(T+1)&1],
// q2/q3 stage B(T+2)->buf[(T+2)&1] (=current, safe: B consumed into regs at
// q0, two barriers earlier); q3 vmcnt(4) lands A(T+1)+B(T+1), keeps B(T+2)
// flying. Clamped tails re-stage identical bytes (benign). Epilogue stores
// pollute vmcnt only conservatively (in-order retire). 1-D grid + XCD
// panel-affinity decode (8 tn-blocks sharing an A panel -> same XCD) to cut
// the 3.3x read over-fetch. apply_pv / legacy V-GEMM / conversions unchanged.

typedef unsigned short u16;
typedef short    bf16x8 __attribute__((ext_vector_type(8)));
typedef unsigned short u16x8 __attribute__((ext_vector_type(8)));
typedef unsigned short u16x4 __attribute__((ext_vector_type(4)));
typedef float    f32x4  __attribute__((ext_vector_type(4)));

typedef __attribute__((address_space(3))) unsigned int       lds_uint;
typedef __attribute__((address_space(1))) const unsigned int gl_uint;

__device__ __forceinline__ void glds16(const void* g, void* l) {
  __builtin_amdgcn_global_load_lds((gl_uint*)g, (lds_uint*)l, 16, 0, 0);
}

__device__ __forceinline__ u16 to_bf16(float f) {
  unsigned u = __float_as_uint(f);
  return (u16)((u + 0x7FFFu + ((u >> 16) & 1u)) >> 16);  // RNE
}
__device__ __forceinline__ float b2f(u16 h) {
  return __uint_as_float(((unsigned)h) << 16);
}

// ---------------- conversion kernels ----------------

__global__ void cvt_x(const float4* __restrict__ in, u16x4* __restrict__ out, int n4) {
  int i = blockIdx.x * 256 + threadIdx.x;
  if (i >= n4) return;
  float4 v = in[i];
  u16x4 o;
  o[0] = to_bf16(v.x); o[1] = to_bf16(v.y); o[2] = to_bf16(v.z); o[3] = to_bf16(v.w);
  out[i] = o;
}

__global__ void transpose_cvt(const float* __restrict__ in, u16* __restrict__ out,
                              int R, int C) {
  __shared__ float t[64][65];
  int c0 = blockIdx.x * 64, r0 = blockIdx.y * 64;
  int tx = threadIdx.x, ty = threadIdx.y;
  #pragma unroll
  for (int i = 0; i < 64; i += 4)
    t[ty + i][tx] = in[(long)(r0 + ty + i) * C + c0 + tx];
  __syncthreads();
  #pragma unroll
  for (int i = 0; i < 64; i += 4)
    out[(long)(c0 + ty + i) * R + r0 + tx] = to_bf16(t[tx][ty + i]);
}

__global__ void concat2(const float* __restrict__ a, const float* __restrict__ b,
                        float* __restrict__ o, int n) {
  int i = blockIdx.x * 256 + threadIdx.x;
  if (i < n) o[i] = a[i];
  else if (i < 2 * n) o[i] = b[i - n];
}

// GROUP_M=4 swizzle (legacy gemm_nt only).
__device__ __forceinline__ void swizzle_tiles(int& tm, int& tn) {
  int nx = gridDim.x;
  int lin = blockIdx.y * nx + blockIdx.x;
  int span = nx * 4;
  int group = lin / span;
  int ing = lin % span;
  tm = group * 4 + (ing & 3);
  tn = ing >> 2;
}

// ---------------- legacy 128x128 NT GEMM (kept for the V projection) --------
__global__ __launch_bounds__(256, 4) void gemm_nt(
    const u16* __restrict__ A, int lda,
    const u16* __restrict__ B, int ldb,
    u16* __restrict__ C1, u16* __restrict__ C2, int splitN, int ldc,
    int Kd, float scale,
    const float* __restrict__ bias, int biasMode)   // 0 none, 1 per-col, 2 per-row
{
  __shared__ u16 SM[2][8192];
  u16* As = SM[0];
  u16* Bs = SM[1];

  int tid = threadIdx.x;
  int wave = tid >> 6, lane = tid & 63;
  int quad = lane >> 4, ln = lane & 15;
  int wm = wave >> 1, wn = wave & 1;
  int tm, tn;
  swizzle_tiles(tm, tn);
  int c8 = lane >> 3, ml = lane & 7;

  const f32x4 fz = {0.f, 0.f, 0.f, 0.f};
  f32x4 acc[4][4];
  #pragma unroll
  for (int i = 0; i < 4; i++)
    #pragma unroll
    for (int j = 0; j < 4; j++) acc[i][j] = fz;

  const u16* Abase = A + (long)(tm * 128 + ml) * lda + c8 * 8;
  const u16* Bbase = B + (long)(tn * 128 + ml) * ldb + c8 * 8;

  for (int kt = 0; kt < Kd; kt += 64) {
    __syncthreads();
    #pragma unroll
    for (int i = 0; i < 4; i++) {
      int mg = wave * 4 + i;
      glds16(Abase + (long)mg * 8 * lda + kt, &As[mg * 512]);
      glds16(Bbase + (long)mg * 8 * ldb + kt, &Bs[mg * 512]);
    }
    __syncthreads();
    #pragma unroll
    for (int ks = 0; ks < 2; ks++) {
      bf16x8 af[4], bfr[4];
      int c = ks * 4 + quad;
      #pragma unroll
      for (int mt = 0; mt < 4; mt++) {
        int m = wm * 64 + mt * 16 + ln;
        af[mt] = *(const bf16x8*)&As[((m >> 3) * 64 + c * 8 + (m & 7)) * 8];
      }
      #pragma unroll
      for (int nt = 0; nt < 4; nt++) {
        int n = wn * 64 + nt * 16 + ln;
        bfr[nt] = *(const bf16x8*)&Bs[((n >> 3) * 64 + c * 8 + (n & 7)) * 8];
      }
      #pragma unroll
      for (int mt = 0; mt < 4; mt++)
        #pragma unroll
        for (int nt = 0; nt < 4; nt++)
          acc[mt][nt] = __builtin_amdgcn_mfma_f32_16x16x32_bf16(af[mt], bfr[nt], acc[mt][nt], 0, 0, 0);
    }
  }

  int rowBase = tm * 128 + wm * 64;
  int colBase = tn * 128 + wn * 64;
  u16* Cw = C1; int outCol = colBase;
  if (colBase >= splitN) { Cw = C2; outCol = colBase - splitN; }
  u16* eb = &SM[0][0] + wave * 4096;

  __syncthreads();
  #pragma unroll
  for (int mt = 0; mt < 4; mt++) {
    #pragma unroll
    for (int nt = 0; nt < 4; nt++) {
      int colL = nt * 16 + ln;
      float bcol = (biasMode == 1) ? bias[colBase + colL] : 0.f;
      #pragma unroll
      for (int r = 0; r < 4; r++) {
        int rowL = mt * 16 + quad * 4 + r;
        float brow = (biasMode == 2) ? bias[rowBase + rowL] : 0.f;
        float v = acc[mt][nt][r] * scale + bcol + brow;
        eb[rowL * 64 + (((colL >> 3) ^ (rowL & 7)) << 3) + (colL & 7)] = to_bf16(v);
      }
    }
  }
  {
    int row = lane;
    long gr = (long)(rowBase + row) * ldc + outCol;
    #pragma unroll
    for (int c = 0; c < 8; c++) {
      u16x8 ch = *(const u16x8*)&eb[row * 64 + ((c ^ (row & 7)) << 3)];
      *(u16x8*)&Cw[gr + c * 8] = ch;
    }
  }
}

// =========== persistent fine-phase 256x256 GEMM kernels (BK=64) ==============
// 8 waves (2m x 4n), per-wave 128x64 acc[8][4]. LDS (u16): A dbuf @0 + (T&1)*
// 16384, B dbuf @32768 + (T&1)*16384, eb @65536 + wave*2048 (32x64). 160 KB.
// Per tile T, 4 fine phases; phase q: {ds_read A-frags 2q,2q+1 (+ all B at
// q0); stage half-tile (q<2: A(T+1), else B(T+2)); barrier; lgkm(0);
// setprio(1); 16 MFMA; setprio(0); [q3: vmcnt(4)]; barrier}.
// Chunk layout: chunk mg (rows mg*8..+8, 64 cols) at mg*512 u16, lane-linear.
// Fragment b128 @ ((m>>3)*64 + c*8 + (m&7))*8 u16, c = ks*4+quad.

// ---------------- persistent S GEMM: E=exp(S) + per-64col sum partials ------
// 1-D grid 256. Decode: g=blk&7 (XCD), s2=blk>>3; p=g+8*(s2>>3) = panel
// (tmg,z); tn=s2&7. All 8 tn-blocks of a panel share the A rows -> one XCD.
__global__ __launch_bounds__(512, 2) void gemm_s256p(
    const u16* __restrict__ Q, const u16* __restrict__ K,
    u16* __restrict__ E1, u16* __restrict__ E2,
    float* __restrict__ statsP, float scale)
{
  __shared__ u16 SM[81920];   // 160 KB

  int blk = blockIdx.x;
  int g = blk & 7, s2 = blk >> 3;
  int p_ = g + 8 * (s2 >> 3);     // panel 0..31
  int tn = s2 & 7;
  int tmg = p_ & 1;
  int z = p_ >> 1;                // 0..15
  int bz = z >> 1, half = z & 1;

  const u16* A = Q + (long)bz * 2097152 + half * 512;
  const u16* B = K + (long)bz * 2097152 + half * 512;
  u16* Ed = (half ? E2 : E1) + (long)bz * 4194304;
  float* sp = statsP + (long)z * 65536;

  int tid = threadIdx.x;
  int wave = tid >> 6, lane = tid & 63, quad = lane >> 4, ln = lane & 15;
  int wm = wave >> 2, wn = wave & 3;
  int c8 = lane >> 3, ml = lane & 7;

  const f32x4 fz = {0.f, 0.f, 0.f, 0.f};
  f32x4 acc[8][4];
  #pragma unroll
  for (int i = 0; i < 8; i++)
    #pragma unroll
    for (int j = 0; j < 4; j++) acc[i][j] = fz;

  const u16* Abase = A + (long)(tmg * 1024 + ml) * 1024 + c8 * 8;
  const u16* Bbase = B + (long)(tn * 256 + ml) * 1024 + c8 * 8;
  u16* eb = SM + 65536 + wave * 2048;
  const int NTT = 32;   // 4 subs x 8 K-tiles (BK=64, K=512)

  // ---- prologue: A(0)->A0, B(0)->B0, B(1)->B1; vmcnt(4) leaves B(1) out ----
  #pragma unroll
  for (int h = 0; h < 2; h++) {
    int hg = h * 16 + wave * 2;
    glds16(Abase + (long)(hg * 8) * 1024,       SM + hg * 512);
    glds16(Abase + (long)(hg * 8 + 8) * 1024,   SM + (hg + 1) * 512);
  }
  #pragma unroll
  for (int h = 0; h < 2; h++) {
    int hg = h * 16 + wave * 2;
    glds16(Bbase + (long)(hg * 8) * 1024,       SM + 32768 + hg * 512);
    glds16(Bbase + (long)(hg * 8 + 8) * 1024,   SM + 32768 + (hg + 1) * 512);
  }
  #pragma unroll
  for (int h = 0; h < 2; h++) {
    int hg = h * 16 + wave * 2;
    glds16(Bbase + (long)(hg * 8) * 1024 + 64,     SM + 49152 + hg * 512);
    glds16(Bbase + (long)(hg * 8 + 8) * 1024 + 64, SM + 49152 + (hg + 1) * 512);
  }
  asm volatile("s_waitcnt vmcnt(4)" ::: "memory");
  __builtin_amdgcn_s_barrier();
  __builtin_amdgcn_sched_barrier(0);

  for (int T = 0; T < NTT; T++) {
    const u16* Ar = SM + (T & 1) * 16384;
    const u16* Br = SM + 32768 + (T & 1) * 16384;
    int Ta = (T + 1 < NTT) ? T + 1 : NTT - 1;
    int Tb = (T + 2 < NTT) ? T + 2 : NTT - 1;
    bf16x8 bfr[2][4];

    #pragma unroll
    for (int q = 0; q < 4; q++) {
      bf16x8 af[2][2];
      #pragma unroll
      for (int dm = 0; dm < 2; dm++) {
        int m = wm * 128 + (q * 2 + dm) * 16 + ln;
        #pragma unroll
        for (int ks = 0; ks < 2; ks++)
          af[dm][ks] = *(const bf16x8*)(Ar + ((m >> 3) * 64 + (ks * 4 + quad) * 8 + (m & 7)) * 8);
      }
      if (q == 0) {
        #pragma unroll
        for (int nt = 0; nt < 4; nt++) {
          int n = wn * 64 + nt * 16 + ln;
          #pragma unroll
          for (int ks = 0; ks < 2; ks++)
            bfr[ks][nt] = *(const bf16x8*)(Br + ((n >> 3) * 64 + (ks * 4 + quad) * 8 + (n & 7)) * 8);
        }
      }
      if (q < 2) {          // stage A(Ta) half q -> A buf[Ta&1]
        int hg = q * 16 + wave * 2;
        u16* dst = SM + (Ta & 1) * 16384;
        long ao = (long)((Ta >> 3) * 256 + hg * 8) * 1024 + ((Ta & 7) << 6);
        glds16(Abase + ao,            dst + hg * 512);
        glds16(Abase + ao + 8 * 1024, dst + (hg + 1) * 512);
      } else {              // stage B(Tb) half q-2 -> B buf[Tb&1]
        int hg = (q - 2) * 16 + wave * 2;
        u16* dst = SM + 32768 + (Tb & 1) * 16384;
        long bo = (long)(hg * 8) * 1024 + ((Tb & 7) << 6);
        glds16(Bbase + bo,            dst + hg * 512);
        glds16(Bbase + bo + 8 * 1024, dst + (hg + 1) * 512);
      }
      __builtin_amdgcn_sched_barrier(0);
      __builtin_amdgcn_s_barrier();
      asm volatile("s_waitcnt lgkmcnt(0)" ::: "memory");
      __builtin_amdgcn_sched_barrier(0);
      __builtin_amdgcn_s_setprio(1);
      #pragma unroll
      for (int ks = 0; ks < 2; ks++)
        #pragma unroll
        for (int dm = 0; dm < 2; dm++)
          #pragma unroll
          for (int nt = 0; nt < 4; nt++)
            acc[q * 2 + dm][nt] = __builtin_amdgcn_mfma_f32_16x16x32_bf16(
                af[dm][ks], bfr[ks][nt], acc[q * 2 + dm][nt], 0, 0, 0);
      __builtin_amdgcn_s_setprio(0);
      __builtin_amdgcn_sched_barrier(0);
      if (q == 3) asm volatile("s_waitcnt vmcnt(4)" ::: "memory");
      __builtin_amdgcn_s_barrier();
      __builtin_amdgcn_sched_barrier(0);
    }

    // ---- in-pipeline epilogue (wave-private eb, 4 chunks of 32 rows) ----
    if ((T & 7) == 7) {
      int sub = T >> 3;
      int rowBase0 = (tmg * 4 + sub) * 256 + wm * 128;
      int colBase = tn * 256 + wn * 64;
      int kb = tn * 4 + wn;
      #pragma unroll
      for (int c2 = 0; c2 < 4; c2++) {
        #pragma unroll
        for (int gg = 0; gg < 2; gg++) {
          #pragma unroll
          for (int nt = 0; nt < 4; nt++) {
            int colL = nt * 16 + ln;
            #pragma unroll
            for (int r = 0; r < 4; r++) {
              int rowL = gg * 16 + quad * 4 + r;
              eb[rowL * 64 + (((colL >> 3) ^ (rowL & 7)) << 3) + (colL & 7)] =
                  to_bf16(__expf(acc[c2 * 2 + gg][nt][r] * scale));
            }
          }
        }
        {
          int row = lane & 31, hf = lane >> 5;
          float L = 0.f;
          u16x8 ch[4];
          #pragma unroll
          for (int cc = 0; cc < 4; cc++) {
            int c = hf * 4 + cc;
            ch[cc] = *(const u16x8*)&eb[row * 64 + ((c ^ (row & 7)) << 3)];
            #pragma unroll
            for (int j = 0; j < 8; j++) L += b2f(ch[cc][j]);
          }
          u16* Ep = Ed + (long)(rowBase0 + c2 * 32 + row) * 2048 + colBase + hf * 32;
          #pragma unroll
          for (int cc = 0; cc < 4; cc++)
            *(u16x8*)&Ep[cc * 8] = ch[cc];
          L += __shfl_xor(L, 32);
          if (hf == 0)
            sp[(rowBase0 + c2 * 32 + row) * 32 + kb] = L;
        }
      }
      #pragma unroll
      for (int i = 0; i < 8; i++)
        #pragma unroll
        for (int j = 0; j < 4; j++) acc[i][j] = fz;
    }
  }
  asm volatile("s_waitcnt vmcnt(0)" ::: "memory");
}

// ---------------- persistent NT GEMM for the QK projection ------------------
// 1-D grid 256: g=blk&7, s2=blk>>3, tmg = g+8*(s2>>3) (0..31), tn=s2&7.
// K=1024 -> 2 subs x 16 K-tiles = 32 continuous tiles/block.
__global__ __launch_bounds__(512, 2) void gemm_nt256p(
    const u16* __restrict__ A, const u16* __restrict__ B,
    u16* __restrict__ C1, u16* __restrict__ C2, int splitN, int ldc,
    float scale, const float* __restrict__ bias, int biasMode)
{
  __shared__ u16 SM[81920];   // 160 KB

  int blk = blockIdx.x;
  int g = blk & 7, s2 = blk >> 3;
  int tmg = g + 8 * (s2 >> 3);    // 0..31
  int tn = s2 & 7;

  int tid = threadIdx.x;
  int wave = tid >> 6, lane = tid & 63, quad = lane >> 4, ln = lane & 15;
  int wm = wave >> 2, wn = wave & 3;
  int c8 = lane >> 3, ml = lane & 7;

  const f32x4 fz = {0.f, 0.f, 0.f, 0.f};
  f32x4 acc[8][4];
  #pragma unroll
  for (int i = 0; i < 8; i++)
    #pragma unroll
    for (int j = 0; j < 4; j++) acc[i][j] = fz;

  const u16* Abase = A + (long)(tmg * 512 + ml) * 1024 + c8 * 8;
  const u16* Bbase = B + (long)(tn * 256 + ml) * 1024 + c8 * 8;
  u16* eb = SM + 65536 + wave * 2048;
  const int NTT = 32;   // 2 subs x 16 K-tiles (BK=64, K=1024)

  #pragma unroll
  for (int h = 0; h < 2; h++) {
    int hg = h * 16 + wave * 2;
    glds16(Abase + (long)(hg * 8) * 1024,       SM + hg * 512);
    glds16(Abase + (long)(hg * 8 + 8) * 1024,   SM + (hg + 1) * 512);
  }
  #pragma unroll
  for (int h = 0; h < 2; h++) {
    int hg = h * 16 + wave * 2;
    glds16(Bbase + (long)(hg * 8) * 1024,       SM + 32768 + hg * 512);
    glds16(Bbase + (long)(hg * 8 + 8) * 1024,   SM + 32768 + (hg + 1) * 512);
  }
  #pragma unroll
  for (int h = 0; h < 2; h++) {
    int hg = h * 16 + wave * 2;
    glds16(Bbase + (long)(hg * 8) * 1024 + 64,     SM + 49152 + hg * 512);
    glds16(Bbase + (long)(hg * 8 + 8) * 1024 + 64, SM + 49152 + (hg + 1) * 512);
  }
  asm volatile("s_waitcnt vmcnt(4)" ::: "memory");
  __builtin_amdgcn_s_barrier();
  __builtin_amdgcn_sched_barrier(0);

  for (int T = 0; T < NTT; T++) {
    const u16* Ar = SM + (T & 1) * 16384;
    const u16* Br = SM + 32768 + (T & 1) * 16384;
    int Ta = (T + 1 < NTT) ? T + 1 : NTT - 1;
    int Tb = (T + 2 < NTT) ? T + 2 : NTT - 1;
    bf16x8 bfr[2][4];

    #pragma unroll
    for (int q = 0; q < 4; q++) {
      bf16x8 af[2][2];
      #pragma unroll
      for (int dm = 0; dm < 2; dm++) {
        int m = wm * 128 + (q * 2 + dm) * 16 + ln;
        #pragma unroll
        for (int ks = 0; ks < 2; ks++)
          af[dm][ks] = *(const bf16x8*)(Ar + ((m >> 3) * 64 + (ks * 4 + quad) * 8 + (m & 7)) * 8);
      }
      if (q == 0) {
        #pragma unroll
        for (int nt = 0; nt < 4; nt++) {
          int n = wn * 64 + nt * 16 + ln;
          #pragma unroll
          for (int ks = 0; ks < 2; ks++)
            bfr[ks][nt] = *(const bf16x8*)(Br + ((n >> 3) * 64 + (ks * 4 + quad) * 8 + (n & 7)) * 8);
        }
      }
      if (q < 2) {
        int hg = q * 16 + wave * 2;
        u16* dst = SM + (Ta & 1) * 16384;
        long ao = (long)((Ta >> 4) * 256 + hg * 8) * 1024 + ((Ta & 15) << 6);
        glds16(Abase + ao,            dst + hg * 512);
        glds16(Abase + ao + 8 * 1024, dst + (hg + 1) * 512);
      } else {
        int hg = (q - 2) * 16 + wave * 2;
        u16* dst = SM + 32768 + (Tb & 1) * 16384;
        long bo = (long)(hg * 8) * 1024 + ((Tb & 15) << 6);
        glds16(Bbase + bo,            dst + hg * 512);
        glds16(Bbase + bo + 8 * 1024, dst + (hg + 1) * 512);
      }
      __builtin_amdgcn_sched_barrier(0);
      __builtin_amdgcn_s_barrier();
      asm volatile("s_waitcnt lgkmcnt(0)" ::: "memory");
      __builtin_amdgcn_sched_barrier(0);
      __builtin_amdgcn_s_setprio(1);
      #pragma unroll
      for (int ks = 0; ks < 2; ks++)
        #pragma unroll
        for (int dm = 0; dm < 2; dm++)
          #pragma unroll
          for (int nt = 0; nt < 4; nt++)
            acc[q * 2 + dm][nt] = __builtin_amdgcn_mfma_f32_16x16x32_bf16(
                af[dm][ks], bfr[ks][nt], acc[q * 2 + dm][nt], 0, 0, 0);
      __builtin_amdgcn_s_setprio(0);
      __builtin_amdgcn_sched_barrier(0);
      if (q == 3) asm volatile("s_waitcnt vmcnt(4)" ::: "memory");
      __builtin_amdgcn_s_barrier();
      __builtin_amdgcn_sched_barrier(0);
    }

    if ((T & 15) == 15) {
      int sub = T >> 4;
      int rowBase0 = (tmg * 2 + sub) * 256 + wm * 128;
      int colBase = tn * 256 + wn * 64;
      u16* Cw = C1; int outCol = colBase;
      if (colBase >= splitN) { Cw = C2; outCol = colBase - splitN; }
      #pragma unroll
      for (int c2 = 0; c2 < 4; c2++) {
        #pragma unroll
        for (int gg = 0; gg < 2; gg++) {
          #pragma unroll
          for (int nt = 0; nt < 4; nt++) {
            int colL = nt * 16 + ln;
            float bcol = (biasMode == 1) ? bias[colBase + colL] : 0.f;
            #pragma unroll
            for (int r = 0; r < 4; r++) {
              int rowL = gg * 16 + quad * 4 + r;
              float brow = (biasMode == 2) ? bias[rowBase0 + c2 * 32 + rowL] : 0.f;
              float v = acc[c2 * 2 + gg][nt][r] * scale + bcol + brow;
              eb[rowL * 64 + (((colL >> 3) ^ (rowL & 7)) << 3) + (colL & 7)] = to_bf16(v);
            }
          }
        }
        {
          int row = lane & 31, hf = lane >> 5;
          u16x8 ch[4];
          #pragma unroll
          for (int cc = 0; cc < 4; cc++) {
            int c = hf * 4 + cc;
            ch[cc] = *(const u16x8*)&eb[row * 64 + ((c ^ (row & 7)) << 3)];
          }
          long gr = (long)(rowBase0 + c2 * 32 + row) * ldc + outCol + hf * 32;
          #pragma unroll
          for (int cc = 0; cc < 4; cc++)
            *(u16x8*)&Cw[gr + cc * 8] = ch[cc];
        }
      }
      #pragma unroll
      for (int i = 0; i < 8; i++)
        #pragma unroll
        for (int j = 0; j < 4; j++) acc[i][j] = fz;
    }
  }
  asm volatile("s_waitcnt vmcnt(0)" ::: "memory");
}

// ---------------- stats reduce: 32 partials -> inv-denominator ----------------
__global__ void stats_reduce(const float* __restrict__ sp, float* __restrict__ so,
                             const float* __restrict__ lamPtr) {
  int gid = blockIdx.x * 256 + threadIdx.x;   // 0..32767
  const float* p = sp + (long)gid * 32;
  float L = 0.f;
  #pragma unroll
  for (int kb = 0; kb < 32; kb++) L += p[kb];
  int half = (gid >> 11) & 1;
  so[gid] = (half ? lamPtr[0] : 1.0f) / L;
}

// ---------------- apply: O = (E1*i1 - E2*i2) @ V ----------------
// (verified round-10 version, unchanged)
__global__ __launch_bounds__(512, 2) void apply_pv(
    const u16* __restrict__ E1, const u16* __restrict__ E2,
    const u16* __restrict__ VT, const float* __restrict__ inv,
    float* __restrict__ Out)
{
  __shared__ u16 Vs[2][32768];    // 2 x [512 d][64 k] packed subtile, 128 KB
  __shared__ u16 Pb[2][4096];     // 2 x [64 q][64 k] packed subtile, 16 KB
  __shared__ float i1s[64], i2s[64];

  const int NT = 32;
  int b = blockIdx.x & 7, qt = blockIdx.x >> 3;
  int q0 = qt * 64;
  int tid = threadIdx.x;
  int wave = tid >> 6, lane = tid & 63, quad = lane >> 4, ln = lane & 15;
  int c8 = lane >> 3, ml = lane & 7;
  int r = tid >> 3, cg8 = tid & 7;            // P producer mapping: 64 rows x 8 col-groups

  const u16* e1p = E1 + ((long)b * 2048 + q0 + r) * 2048 + cg8 * 8;
  const u16* e2p = E2 + ((long)b * 2048 + q0 + r) * 2048 + cg8 * 8;
  const u16* Vbase = VT + (long)b * 2048;     // row stride 16384 (u16)
  int pw = (r >> 3) * 512 + cg8 * 64 + (r & 7) * 8;   // packed P write idx (u16)

  const f32x4 fz = {0.f, 0.f, 0.f, 0.f};
  f32x4 acc[4][4];
  #pragma unroll
  for (int i = 0; i < 4; i++)
    #pragma unroll
    for (int j = 0; j < 4; j++) acc[i][j] = fz;

  // ---- prologue ----
  if (tid < 64)       i1s[tid]       = inv[(long)(b * 2 + 0) * 2048 + q0 + tid];
  else if (tid < 128) i2s[tid - 64]  = inv[(long)(b * 2 + 1) * 2048 + q0 + (tid - 64)];
  u16x8 a1 = *(const u16x8*)(e1p);            // E(0), compiler-tracked
  u16x8 a2 = *(const u16x8*)(e2p);
  __builtin_amdgcn_sched_barrier(0);
  #pragma unroll
  for (int i = 0; i < 8; i++) {               // V(0) -> Vs[0]
    int dg = wave * 8 + i;
    glds16(Vbase + (long)(dg * 8 + ml) * 16384 + c8 * 8, &Vs[0][dg * 512]);
  }
  __builtin_amdgcn_sched_barrier(0);
  asm volatile("s_waitcnt lgkmcnt(0)" ::: "memory");   // i1s/i2s stores done
  __builtin_amdgcn_s_barrier();                        // i1s visible
  __builtin_amdgcn_sched_barrier(0);
  float i1 = i1s[r], i2 = i2s[r];
  {
    u16x8 o;
    #pragma unroll
    for (int j = 0; j < 8; j++)
      o[j] = to_bf16(b2f(a1[j]) * i1 - b2f(a2[j]) * i2);
    *(u16x8*)&Pb[0][pw] = o;                  // P(0)
  }
  a1 = *(const u16x8*)(e1p + 64);             // E(1)
  a2 = *(const u16x8*)(e2p + 64);
  __builtin_amdgcn_sched_barrier(0);
  asm volatile("s_waitcnt lgkmcnt(0)" ::: "memory");   // P(0) write done
  asm volatile("s_waitcnt vmcnt(2)" ::: "memory");     // V(0) landed, E(1) flying
  __builtin_amdgcn_sched_barrier(0);
  __builtin_amdgcn_s_barrier();
  __builtin_amdgcn_sched_barrier(0);

  // ---- main loop ----
  for (int t = 0; t < NT; t++) {
    const int p = t & 1;
    const u16* Vr = &Vs[p][0];
    const u16* Pr = &Pb[p][0];
    u16* Vw = &Vs[p ^ 1][0];
    u16* Pw = &Pb[p ^ 1][0];
    int ktv = ((t + 1 < NT) ? (t + 1) : (NT - 1)) << 6;   // V(t+1)
    int kte = ((t + 2 < NT) ? (t + 2) : (NT - 1)) << 6;   // E(t+2)
    bf16x8 vf[2][4];

    #pragma unroll
    for (int q = 0; q < 4; q++) {
      bf16x8 pf[2];
      #pragma unroll
      for (int ks = 0; ks < 2; ks++) {
        int m = q * 16 + ln;
        pf[ks] = *(const bf16x8*)&Pr[((m >> 3) * 64 + (ks * 4 + quad) * 8 + (m & 7)) * 8];
      }
      if (q == 0) {
        #pragma unroll
        for (int ks = 0; ks < 2; ks++)
          #pragma unroll
          for (int nt = 0; nt < 4; nt++) {
            int d = wave * 64 + nt * 16 + ln;
            vf[ks][nt] = *(const bf16x8*)&Vr[((d >> 3) * 64 + (ks * 4 + quad) * 8 + (d & 7)) * 8];
          }
      }
      // stage V(t+1): 2 glds16 per wave per phase
      #pragma unroll
      for (int i = 0; i < 2; i++) {
        int dg = wave * 8 + q * 2 + i;
        glds16(Vbase + (long)(dg * 8 + ml) * 16384 + ktv + c8 * 8, Vw + dg * 512);
      }
      if (q == 3) {
        __builtin_amdgcn_sched_barrier(0);
        // compiler inserts the wait for a1/a2 (E(t+1)) here; V(t+1)x8 stay out
        u16x8 o;
        #pragma unroll
        for (int j = 0; j < 8; j++)
          o[j] = to_bf16(b2f(a1[j]) * i1 - b2f(a2[j]) * i2);
        *(u16x8*)&Pw[pw] = o;                             // P(t+1)
        a1 = *(const u16x8*)(e1p + kte);                  // E(t+2)
        a2 = *(const u16x8*)(e2p + kte);
      }
      __builtin_amdgcn_sched_barrier(0);
      __builtin_amdgcn_s_barrier();
      asm volatile("s_waitcnt lgkmcnt(0)" ::: "memory");
      __builtin_amdgcn_sched_barrier(0);
      __builtin_amdgcn_s_setprio(1);
      #pragma unroll
      for (int ks = 0; ks < 2; ks++)
        #pragma unroll
        for (int nt = 0; nt < 4; nt++)
          acc[q][nt] = __builtin_amdgcn_mfma_f32_16x16x32_bf16(pf[ks], vf[ks][nt], acc[q][nt], 0, 0, 0);
      __builtin_amdgcn_s_setprio(0);
      __builtin_amdgcn_sched_barrier(0);
      if (q == 3) asm volatile("s_waitcnt vmcnt(2)" ::: "memory");  // V(t+1) landed
      __builtin_amdgcn_s_barrier();
      __builtin_amdgcn_sched_barrier(0);
    }
  }

  #pragma unroll
  for (int mt = 0; mt < 4; mt++)
    #pragma unroll
    for (int nt = 0; nt < 4; nt++)
      #pragma unroll
      for (int r2 = 0; r2 < 4; r2++)
        Out[((long)b * 2048 + q0 + mt * 16 + quad * 4 + r2) * 512 + wave * 64 + nt * 16 + ln] =
            acc[mt][nt][r2];
}

// ---------------- launch ----------------

extern "C" void kernel_launch(void* const* d_in, const int* in_sizes, int n_in,
                              void* d_out, int out_size, void* d_ws, size_t ws_size,
                              hipStream_t stream)
{
  const float* X   = (const float*)d_in[0];
  const float* lam = (const float*)d_in[1];
  const float* Wq  = (const float*)d_in[2];
  const float* bq  = (const float*)d_in[3];
  const float* Wk  = (const float*)d_in[4];
  const float* bk  = (const float*)d_in[5];
  const float* Wv  = (const float*)d_in[6];
  const float* bv  = (const float*)d_in[7];
  float* Out = (float*)d_out;
  char* ws = (char*)d_ws;

  u16*  WqkT   = (u16*)(ws + 0);           //  4 MB [2048][1024]
  u16*  WvT    = (u16*)(ws + 4194304);     //  1 MB [512][1024]
  float* bqk   = (float*)(ws + 5242880);   //  8 KB [2048]
  u16*  Qb     = (u16*)(ws + 6291456);     // 32 MB [16384][1024]
  u16*  Kb     = (u16*)(ws + 39845888);    // 32 MB [16384][1024]
  u16*  VTb    = (u16*)(ws + 73400320);    // 16 MB [512][16384]
  u16*  Xb     = (u16*)(ws + 90177536);    // 32 MB [16384][1024]
  u16*  E1     = (u16*)(ws + 90177536);    // 64 MB, overlaps Xb (Xb dead first)
  u16*  E2     = (u16*)(ws + 157286400);   // 64 MB
  float* statsP= (float*)(ws + 224395264); //  4 MB [8][2][2048][32]
  float* invD  = (float*)(ws + 228589568); // 128 KB [8][2][2048]

  cvt_x<<<16384, 256, 0, stream>>>((const float4*)X, (u16x4*)Xb, 4194304);
  transpose_cvt<<<dim3(16, 16), dim3(64, 4), 0, stream>>>(Wq, WqkT, 1024, 1024);
  transpose_cvt<<<dim3(16, 16), dim3(64, 4), 0, stream>>>(Wk, WqkT + 1024 * 1024, 1024, 1024);
  transpose_cvt<<<dim3(8, 16),  dim3(64, 4), 0, stream>>>(Wv, WvT, 1024, 512);
  concat2<<<8, 256, 0, stream>>>(bq, bk, bqk, 1024);

  // [Q|K] = Xb @ WqkT^T + bqk, persistent fine-phase 256^2 tiles
  gemm_nt256p<<<256, 512, 0, stream>>>(Xb, WqkT, Qb, Kb, 1024, 1024,
                                       1.0f, bqk, 1);
  // V^T[d][m] = sum_e WvT[d][e]*Xb[m][e] + bv[d]  (legacy 128^2 kernel)
  gemm_nt<<<dim3(128, 4), 256, 0, stream>>>(WvT, 1024, Xb, 1024,
                                            VTb, VTb, 1 << 30, 16384,
                                            1024, 1.0f, bv, 2);

  const float s = 0.044194173824159216f;  // 1/sqrt(512)
  gemm_s256p<<<256, 512, 0, stream>>>(Qb, Kb, E1, E2, statsP, s);

  stats_reduce<<<128, 256, 0, stream>>>(statsP, invD, lam);
  apply_pv<<<256, 512, 0, stream>>>(E1, E2, VTb, invD, Out);
}